// Round 7
// baseline (584.093 us; speedup 1.0000x reference)
//
#include <hip/hip_runtime.h>

#define BB 2
#define NN 20000
#define HH 128
#define EE 200000
#define EBLK 3125   // EE / 64
#define NBLK 79     // ceil(NN/256)

typedef unsigned short u16;
typedef __attribute__((ext_vector_type(4))) float f32x4;
typedef __bf16 bf16x8 __attribute__((ext_vector_type(8)));

#define MFMA(a, b, c) __builtin_amdgcn_mfma_f32_16x16x32_bf16((a), (b), (c), 0, 0, 0)

__device__ __forceinline__ float bf2f(u16 u) {
    union { unsigned int i; float f; } v; v.i = ((unsigned int)u) << 16; return v.f;
}
__device__ __forceinline__ u16 f2bf(float f) {
    union { __bf16 h; u16 u; } v; v.h = (__bf16)f; return v.u;
}
__device__ __forceinline__ float fastrcp(float x) {
    float r; asm volatile("v_rcp_f32 %0, %1" : "=v"(r) : "v"(x)); return r;
}
__device__ __forceinline__ float silu_f(float z) {
    return z * fastrcp(1.f + __expf(-z));
}
// flag-routed load: f32 raw or bf16 raw
__device__ __forceinline__ float ldv(const void* p, long i, int f) {
    return f ? ((const float*)p)[i] : bf2f(((const u16*)p)[i]);
}

// ---------------- dtype detection ----------------
__global__ void detect_kernel(const u16* __restrict__ f, int* __restrict__ flag) {
    int tid = threadIdx.x;
    u16 v = f[tid * 2];
    int e = (v >> 7) & 0xFF;
    int ok = (e >= 101 && e <= 143) ? 1 : 0;
    __shared__ int cnt;
    if (tid == 0) cnt = 0;
    __syncthreads();
    atomicAdd(&cnt, ok);
    __syncthreads();
    if (tid == 0) *flag = (cnt < 200) ? 1 : 0;   // 1 => inputs are float32
}

// ---------------- prep: zero accumulators (flag-routed) + CSR counters -----
__global__ __launch_bounds__(256) void prep_kernel(void* outp, float* __restrict__ ws_msg,
                                                   float* __restrict__ ws_pos,
                                                   int* __restrict__ cnt,
                                                   const int* __restrict__ flag) {
    int i = blockIdx.x * 256 + threadIdx.x;
    if (i < 5240000) {
        if (*flag) ((float*)outp)[i] = 0.f;
        else if (i < 5120000) ws_msg[i] = 0.f;
        else ws_pos[i - 5120000] = 0.f;
    } else {
        int j = i - 5240000;
        if (j < 40000) cnt[j] = 0;
    }
}

// ---------------- weight fragment permutation (reads raw, flag-routed) -----
#define FTOT 180224
struct P8 { const void* w[8]; };

__global__ __launch_bounds__(256) void make_frag_all(P8 ws, u16* __restrict__ fbase,
                                                     const int* __restrict__ flag) {
    static const int foff[9] = { 0, 32768, 49152, 65536, 98304, 114688, 131072, 163840, 180224 };
    int i = blockIdx.x * 256 + threadIdx.x;
    if (i >= FTOT) return;
    int isf = *flag;
    int t = 0;
#pragma unroll 1
    while (i >= foff[t + 1]) ++t;
    int j = i - foff[t];
    int jj = j & 7, lane = (j >> 3) & 63, nt = (j >> 9) & 7, kt = j >> 12;
    int k = kt * 32 + ((lane >> 4) * 8) + jj;
    int n = nt * 16 + (lane & 15);
    fbase[i] = f2bf(ldv(ws.w[t], (long)k * 128 + n, isf));
}

// ---------------- CSR build ----------------
__global__ void count2_kernel(const int* __restrict__ eu, const int* __restrict__ ed,
                              int* __restrict__ cu, int* __restrict__ cd) {
    int e = blockIdx.x * 256 + threadIdx.x;
    if (e < EE) atomicAdd(&cu[eu[EE + e]], 1);
    else { e -= EE; if (e < EE) atomicAdd(&cd[ed[EE + e]], 1); }
}

struct SP { const int* cnt[2]; int* cur[2]; int* bsum[2]; };

__global__ __launch_bounds__(256) void scan1_kernel(SP p) {
    int half = blockIdx.x / NBLK;
    int b = blockIdx.x - half * NBLK;
    int t = threadIdx.x;
    int i = b * 256 + t;
    __shared__ int buf[256];
    int v = (i < NN) ? p.cnt[half][i] : 0;
    buf[t] = v;
    __syncthreads();
    for (int s = 1; s < 256; s <<= 1) {
        int x = (t >= s) ? buf[t - s] : 0;
        __syncthreads();
        buf[t] += x;
        __syncthreads();
    }
    if (i < NN) p.cur[half][i] = buf[t] - v;   // exclusive within block
    if (t == 255) p.bsum[half][b] = buf[255];
}

__global__ __launch_bounds__(256) void scan2_kernel(int* __restrict__ bu, int* __restrict__ bd) {
    __shared__ int buf[2][128];
    int half = threadIdx.x >> 7, t = threadIdx.x & 127;
    int* bs = half ? bd : bu;
    int v = (t < NBLK) ? bs[t] : 0;
    buf[half][t] = v;
    __syncthreads();
    for (int s = 1; s < 128; s <<= 1) {
        int x = (t >= s) ? buf[half][t - s] : 0;
        __syncthreads();
        buf[half][t] += x;
        __syncthreads();
    }
    if (t < NBLK) bs[t] = buf[half][t] - v;    // exclusive block offsets
}

// scatter with fused bsum add (scan3 folded in)
__global__ void scatter2_kernel(const int* __restrict__ eu, const int* __restrict__ ed,
                                int* __restrict__ cu, const int* __restrict__ bu,
                                int* __restrict__ cd, const int* __restrict__ bd,
                                int* __restrict__ su, int* __restrict__ sd) {
    int e = blockIdx.x * 256 + threadIdx.x;
    if (e < EE) {
        int d = eu[EE + e];
        int p = atomicAdd(&cu[d], 1) + bu[d >> 8];
        su[p] = e;
    } else {
        e -= EE;
        if (e < EE) {
            int d = ed[EE + e];
            int p = atomicAdd(&cd[d], 1) + bd[d >> 8];
            sd[p] = e;
        }
    }
}

// ---------------- node precompute: Y = feat @ W1-half (+bias on dst half) --
__global__ __launch_bounds__(256) void nodey_kernel(
    const void* __restrict__ rawfeat,
    const u16* __restrict__ f_m1u, const u16* __restrict__ f_m1d,
    const void* __restrict__ b1u, const void* __restrict__ b1d,
    u16* __restrict__ Ysu, u16* __restrict__ Ydu,
    u16* __restrict__ Ysd, u16* __restrict__ Ydd,
    const int* __restrict__ flag)
{
    const int tid = threadIdx.x;
    const int lane = tid & 63;
    const int wv = tid >> 6;            // 0..3 -> Ysu, Ydu, Ysd, Ydd
    const int row0 = blockIdx.x * 64;
    const int isf = *flag;

    __shared__ u16 sF[64][136];

    if (isf) {
        const float* fp = (const float*)rawfeat + (size_t)row0 * HH;
        for (int i = tid; i < 1024; i += 256) {
            int r = i >> 4, c = (i & 15) * 8;
            float4 v0 = *(const float4*)(fp + (size_t)r * HH + c);
            float4 v1 = *(const float4*)(fp + (size_t)r * HH + c + 4);
            uint4 o;
            o.x = (unsigned)f2bf(v0.x) | ((unsigned)f2bf(v0.y) << 16);
            o.y = (unsigned)f2bf(v0.z) | ((unsigned)f2bf(v0.w) << 16);
            o.z = (unsigned)f2bf(v1.x) | ((unsigned)f2bf(v1.y) << 16);
            o.w = (unsigned)f2bf(v1.z) | ((unsigned)f2bf(v1.w) << 16);
            *(uint4*)&sF[r][c] = o;
        }
    } else {
        const uint4* fp = (const uint4*)((const u16*)rawfeat + (size_t)row0 * HH);
        for (int i = tid; i < 1024; i += 256) {
            int r = i >> 4, c = i & 15;
            *(uint4*)&sF[r][c * 8] = fp[i];
        }
    }
    __syncthreads();

    const int mrow = lane & 15;
    const int kq = (lane >> 4) * 8;
    const int crow = (lane >> 4) * 4;
    const int ccol = lane & 15;

    const u16* frag = (wv < 2) ? f_m1u : f_m1d;
    const int ktb = (wv & 1) * 4;       // src half: kt 0..3, dst half: kt 4..7
    u16* Yout = (wv == 0) ? Ysu : (wv == 1) ? Ydu : (wv == 2) ? Ysd : Ydd;
    const void* bias = (wv == 1) ? b1u : (wv == 3) ? b1d : (const void*)0;

#pragma unroll 1
    for (int hf = 0; hf < 2; ++hf) {
        f32x4 acc[4][4];
#pragma unroll
        for (int mt = 0; mt < 4; ++mt)
#pragma unroll
            for (int nt = 0; nt < 4; ++nt) acc[mt][nt] = (f32x4){0.f, 0.f, 0.f, 0.f};
#pragma unroll
        for (int kt = 0; kt < 4; ++kt) {
            const int kk = kt * 32 + kq;
            bf16x8 bw[4];
#pragma unroll
            for (int nt = 0; nt < 4; ++nt)
                bw[nt] = *(const bf16x8*)(frag +
                    (size_t)((((ktb + kt) * 8 + hf * 4 + nt) * 64 + lane) * 8));
#pragma unroll
            for (int mt = 0; mt < 4; ++mt) {
                bf16x8 a = *(const bf16x8*)(&sF[0][0] + (mt * 16 + mrow) * 136 + kk);
#pragma unroll
                for (int nt = 0; nt < 4; ++nt) acc[mt][nt] = MFMA(a, bw[nt], acc[mt][nt]);
            }
        }
#pragma unroll
        for (int mt = 0; mt < 4; ++mt) {
#pragma unroll
            for (int nt = 0; nt < 4; ++nt) {
                const int col = (hf * 4 + nt) * 16 + ccol;
                const float bb = bias ? ldv(bias, col, isf) : 0.f;
#pragma unroll
                for (int r = 0; r < 4; ++r) {
                    const int row = mt * 16 + crow + r;
                    Yout[(size_t)(row0 + row) * HH + col] = f2bf(acc[mt][nt][r] + bb);
                }
            }
        }
    }
}

// ---------------- edge kernel ----------------
struct EP {
    const int* eidx; const int* es;
    const void* deg; const void* w1;      // w1 = raw w_msg1 base (w1last = row 256)
    const void* bias2; const void* biasp1; const void* wp2; const void* biasp2;
    const u16* fW2; const u16* fP1;
    const u16* Ys; const u16* Yd;
};

__global__ __launch_bounds__(512, 8) void edge_kernel(
    const void* __restrict__ posit, EP up, EP dn,
    float* __restrict__ ws_msg, float* __restrict__ ws_pos,
    void* __restrict__ outp, const int* __restrict__ flag)
{
    const int tid = threadIdx.x;
    const int lane = tid & 63;
    const int wv = tid >> 6;              // 0..7 = n-tile
    const int half = blockIdx.x / (BB * EBLK);
    const int rem = blockIdx.x - half * (BB * EBLK);
    const int bb = rem / EBLK;
    const int s0 = (rem - bb * EBLK) * 64;
    const EP P = half ? dn : up;
    const int isf = *flag;
    float* msg_acc = isf ? (float*)outp : ws_msg;
    float* pos_acc = isf ? (float*)outp + 5120000 : ws_pos;

    __shared__ u16 sX[64][136];   // layer1 out -> pos-hidden
    __shared__ u16 sY[64][136];   // messages
    __shared__ float sRel[64][3];
    __shared__ float sDist[64];
    __shared__ float sInv[64];
    __shared__ int sSrc[64], sDst[64];

    if (tid < 64) {
        int e = P.es[s0 + tid];
        int s = P.eidx[e];
        int d = P.eidx[EE + e];
        sSrc[tid] = s; sDst[tid] = d;
        sInv[tid] = 1.f / fmaxf(ldv(P.deg, d, isf), 1.f);
        long pb = ((long)bb * NN + s) * 3, qb = ((long)bb * NN + d) * 3;
        float dx = ldv(posit, pb + 0, isf) - ldv(posit, qb + 0, isf);
        float dy = ldv(posit, pb + 1, isf) - ldv(posit, qb + 1, isf);
        float dz = ldv(posit, pb + 2, isf) - ldv(posit, qb + 2, isf);
        sRel[tid][0] = dx; sRel[tid][1] = dy; sRel[tid][2] = dz;
        sDist[tid] = sqrtf(dx * dx + dy * dy + dz * dz);
    }
    __syncthreads();   // B0

    // fused layer1: silu(Ysrc[src] + Ydst[dst] + dist*w1last) -> sX
    {
        const int r = tid >> 3, c0 = (tid & 7) * 16;
        const u16* ys = P.Ys + ((size_t)bb * NN + sSrc[r]) * HH + c0;
        const u16* yd = P.Yd + ((size_t)bb * NN + sDst[r]) * HH + c0;
        uint4 a0 = *(const uint4*)ys, a1 = *(const uint4*)(ys + 8);
        uint4 b0 = *(const uint4*)yd, b1 = *(const uint4*)(yd + 8);
        const float dist = sDist[r];
        const unsigned* ap = (const unsigned*)&a0;   // a0,a1 contiguous on stack? no —
        uint4 av[2] = { a0, a1 }, bv[2] = { b0, b1 };
        uint4 ov[2];
#pragma unroll
        for (int h = 0; h < 2; ++h) {
            const unsigned* aa = (const unsigned*)&av[h];
            const unsigned* bbp = (const unsigned*)&bv[h];
            unsigned* oo = (unsigned*)&ov[h];
#pragma unroll
            for (int j = 0; j < 4; ++j) {
                int cc = c0 + h * 8 + j * 2;
                float z0 = bf2f((u16)(aa[j] & 0xffff)) + bf2f((u16)(bbp[j] & 0xffff))
                         + dist * ldv(P.w1, 32768 + cc, isf);
                float z1 = bf2f((u16)(aa[j] >> 16)) + bf2f((u16)(bbp[j] >> 16))
                         + dist * ldv(P.w1, 32768 + cc + 1, isf);
                oo[j] = (unsigned)f2bf(silu_f(z0)) | ((unsigned)f2bf(silu_f(z1)) << 16);
            }
        }
        *(uint4*)&sX[r][c0] = ov[0];
        *(uint4*)&sX[r][c0 + 8] = ov[1];
        (void)ap;
    }
    __syncthreads();   // B1

    const int nt = wv;
    const int mrow = lane & 15;
    const int kq = (lane >> 4) * 8;
    const int crow = (lane >> 4) * 4;
    const int ccol = lane & 15;
    const int col = nt * 16 + ccol;

    f32x4 acc[4];
#pragma unroll
    for (int mt = 0; mt < 4; ++mt) acc[mt] = (f32x4){0.f, 0.f, 0.f, 0.f};

    // ----- msg layer 2 : sX @ W2 + b2 = messages -> sY (K=128) -----
#pragma unroll
    for (int kt = 0; kt < 4; ++kt) {
        const int kk = kt * 32 + kq;
        bf16x8 bw = *(const bf16x8*)(P.fW2 + (size_t)(((kt * 8 + nt) * 64 + lane) * 8));
#pragma unroll
        for (int mt = 0; mt < 4; ++mt) {
            bf16x8 a = *(const bf16x8*)(&sX[0][0] + (mt * 16 + mrow) * 136 + kk);
            acc[mt] = MFMA(a, bw, acc[mt]);
        }
    }
    {
        const float bb2 = ldv(P.bias2, col, isf);
#pragma unroll
        for (int mt = 0; mt < 4; ++mt) {
#pragma unroll
            for (int r = 0; r < 4; ++r) {
                const int row = mt * 16 + crow + r;
                sY[row][col] = f2bf(acc[mt][r] + bb2);
            }
        }
    }
    __syncthreads();   // B2: sY complete; all sX reads done

    // ----- pos layer 1 : silu(messages @ P1 + bp1) -> sX (K=128) -----
#pragma unroll
    for (int mt = 0; mt < 4; ++mt) acc[mt] = (f32x4){0.f, 0.f, 0.f, 0.f};
#pragma unroll
    for (int kt = 0; kt < 4; ++kt) {
        const int kk = kt * 32 + kq;
        bf16x8 bw = *(const bf16x8*)(P.fP1 + (size_t)(((kt * 8 + nt) * 64 + lane) * 8));
#pragma unroll
        for (int mt = 0; mt < 4; ++mt) {
            bf16x8 a = *(const bf16x8*)(&sY[0][0] + (mt * 16 + mrow) * 136 + kk);
            acc[mt] = MFMA(a, bw, acc[mt]);
        }
    }

    // segment-reduced scatter of messages (rows sorted by dst)
    {
        const int scol = tid & 127;
        const int r0 = (tid >> 7) * 16;
        float accv = 0.f;
        int dprev = sDst[r0];
        float invprev = sInv[r0];
#pragma unroll 1
        for (int r = r0; r < r0 + 16; ++r) {
            int dcur = sDst[r];
            if (dcur != dprev) {
                unsafeAtomicAdd(&msg_acc[((size_t)bb * NN + dprev) * HH + scol], accv * invprev);
                accv = 0.f; dprev = dcur; invprev = sInv[r];
            }
            accv += bf2f(sY[r][scol]);
        }
        unsafeAtomicAdd(&msg_acc[((size_t)bb * NN + dprev) * HH + scol], accv * invprev);
    }

    // pos1 epilogue -> sX
    {
        const float bb2 = ldv(P.biasp1, col, isf);
#pragma unroll
        for (int mt = 0; mt < 4; ++mt) {
#pragma unroll
            for (int r = 0; r < 4; ++r) {
                const int row = mt * 16 + crow + r;
                sX[row][col] = f2bf(silu_f(acc[mt][r] + bb2));
            }
        }
    }
    __syncthreads();   // B3

    // ----- pos layer 2 : tanh(hidden @ p2 + bp2) ; scatter wgt*rel_pos -----
    {
        const int r = tid >> 3, q = tid & 7;
        const unsigned* t32 = (const unsigned*)&sX[r][q * 16];
        float p = 0.f;
#pragma unroll
        for (int k = 0; k < 8; ++k) {
            unsigned a = t32[k];
            float w0 = ldv(P.wp2, q * 16 + 2 * k, isf);
            float w1 = ldv(P.wp2, q * 16 + 2 * k + 1, isf);
            p = fmaf(bf2f((u16)(a & 0xffff)), w0, p);
            p = fmaf(bf2f((u16)(a >> 16)), w1, p);
        }
        p += __shfl_xor(p, 1);
        p += __shfl_xor(p, 2);
        p += __shfl_xor(p, 4);
        if (q == 0) {
            float wgt = tanhf(p + ldv(P.biasp2, 0, isf));
            const size_t pb = ((size_t)bb * NN + sDst[r]) * 3;
            unsafeAtomicAdd(&pos_acc[pb + 0], wgt * sRel[r][0]);
            unsafeAtomicAdd(&pos_acc[pb + 1], wgt * sRel[r][1]);
            unsafeAtomicAdd(&pos_acc[pb + 2], wgt * sRel[r][2]);
        }
    }
}

// ---------------- update + fused pos output ----------------
__global__ __launch_bounds__(256) void update_kernel(
    const void* __restrict__ rawfeat, const void* __restrict__ rawpos,
    const u16* __restrict__ fU1, const void* __restrict__ bu1,
    const u16* __restrict__ fU2, const void* __restrict__ bu2,
    void* __restrict__ outp, float* __restrict__ ws_msg, float* __restrict__ ws_pos,
    const int* __restrict__ flag)
{
    const int tid = threadIdx.x;
    const int lane = tid & 63;
    const int wv = tid >> 6;
    const int row0 = blockIdx.x * 64;
    const int isf = *flag;
    const float* magg = isf ? (const float*)outp : ws_msg;
    const float* pacc = isf ? (const float*)outp + 5120000 : ws_pos;

    __shared__ u16 sA[64][136];   // features (bf16)
    __shared__ u16 sB[64][136];   // msg_acc -> hidden (reused)

    if (isf) {
        const float* fp = (const float*)rawfeat + (size_t)row0 * HH;
        for (int i = tid; i < 1024; i += 256) {
            int r = i >> 4, c = (i & 15) * 8;
            float4 v0 = *(const float4*)(fp + (size_t)r * HH + c);
            float4 v1 = *(const float4*)(fp + (size_t)r * HH + c + 4);
            uint4 o;
            o.x = (unsigned)f2bf(v0.x) | ((unsigned)f2bf(v0.y) << 16);
            o.y = (unsigned)f2bf(v0.z) | ((unsigned)f2bf(v0.w) << 16);
            o.z = (unsigned)f2bf(v1.x) | ((unsigned)f2bf(v1.y) << 16);
            o.w = (unsigned)f2bf(v1.z) | ((unsigned)f2bf(v1.w) << 16);
            *(uint4*)&sA[r][c] = o;
        }
    } else {
        const uint4* fp = (const uint4*)((const u16*)rawfeat + (size_t)row0 * HH);
        for (int i = tid; i < 1024; i += 256) {
            int r = i >> 4, c = i & 15;
            *(uint4*)&sA[r][c * 8] = fp[i];
        }
    }
    {
        const float4* am = (const float4*)(magg) + (size_t)row0 * 32;
        for (int i = tid; i < 2048; i += 256) {
            int r = i >> 5;
            float4 v = am[i];
            int c = (i & 31) * 4;
            sB[r][c + 0] = f2bf(v.x);
            sB[r][c + 1] = f2bf(v.y);
            sB[r][c + 2] = f2bf(v.z);
            sB[r][c + 3] = f2bf(v.w);
        }
    }
    __syncthreads();

    const int nt0 = wv * 2;
    const int mrow = lane & 15;
    const int kq = (lane >> 4) * 8;
    const int crow = (lane >> 4) * 4;
    const int ccol = lane & 15;

    f32x4 acc[4][2];
#pragma unroll
    for (int mt = 0; mt < 4; ++mt) {
        acc[mt][0] = (f32x4){0.f, 0.f, 0.f, 0.f};
        acc[mt][1] = (f32x4){0.f, 0.f, 0.f, 0.f};
    }
#pragma unroll
    for (int kt = 0; kt < 8; ++kt) {
        const u16* Xb = (kt < 4) ? &sA[0][0] : &sB[0][0];
        const int kk = (kt & 3) * 32 + kq;
        bf16x8 bw0 = *(const bf16x8*)(fU1 + (size_t)(((kt * 8 + nt0) * 64 + lane) * 8));
        bf16x8 bw1 = *(const bf16x8*)(fU1 + (size_t)(((kt * 8 + nt0 + 1) * 64 + lane) * 8));
#pragma unroll
        for (int mt = 0; mt < 4; ++mt) {
            bf16x8 a = *(const bf16x8*)(Xb + (mt * 16 + mrow) * 136 + kk);
            acc[mt][0] = MFMA(a, bw0, acc[mt][0]);
            acc[mt][1] = MFMA(a, bw1, acc[mt][1]);
        }
    }
    __syncthreads();

#pragma unroll
    for (int mt = 0; mt < 4; ++mt) {
#pragma unroll
        for (int n2 = 0; n2 < 2; ++n2) {
            const int col = (nt0 + n2) * 16 + ccol;
            const float bb = ldv(bu1, col, isf);
#pragma unroll
            for (int r = 0; r < 4; ++r) {
                const int row = mt * 16 + crow + r;
                sB[row][col] = f2bf(silu_f(acc[mt][n2][r] + bb));
            }
        }
    }
    __syncthreads();

#pragma unroll
    for (int mt = 0; mt < 4; ++mt) {
        acc[mt][0] = (f32x4){0.f, 0.f, 0.f, 0.f};
        acc[mt][1] = (f32x4){0.f, 0.f, 0.f, 0.f};
    }
#pragma unroll
    for (int kt = 0; kt < 4; ++kt) {
        const int kk = kt * 32 + kq;
        bf16x8 bw0 = *(const bf16x8*)(fU2 + (size_t)(((kt * 8 + nt0) * 64 + lane) * 8));
        bf16x8 bw1 = *(const bf16x8*)(fU2 + (size_t)(((kt * 8 + nt0 + 1) * 64 + lane) * 8));
#pragma unroll
        for (int mt = 0; mt < 4; ++mt) {
            bf16x8 a = *(const bf16x8*)(&sB[0][0] + (mt * 16 + mrow) * 136 + kk);
            acc[mt][0] = MFMA(a, bw0, acc[mt][0]);
            acc[mt][1] = MFMA(a, bw1, acc[mt][1]);
        }
    }
#pragma unroll
    for (int mt = 0; mt < 4; ++mt) {
#pragma unroll
        for (int n2 = 0; n2 < 2; ++n2) {
            const int col = (nt0 + n2) * 16 + ccol;
            const float bb = ldv(bu2, col, isf);
#pragma unroll
            for (int r = 0; r < 4; ++r) {
                const int row = mt * 16 + crow + r;
                const size_t idx = (size_t)(row0 + row) * HH + col;
                if (isf) {
                    float base = ((const float*)rawfeat)[idx];
                    ((float*)outp)[idx] = acc[mt][n2][r] + bb + base;
                } else {
                    float base = bf2f(sA[row][col]);
                    ((u16*)outp)[idx] = f2bf(acc[mt][n2][r] + bb + base);
                }
            }
        }
    }

    // fused positions output: 3 elems per node row (192 per block)
    if (tid < 192) {
        int i = row0 * 3 + tid;
        float x = pacc[i];
        if (isf) {
            float base = ((const float*)rawpos)[i];
            ((float*)outp)[5120000 + i] = base + 0.5f * x;
        } else {
            float base = bf2f(((const u16*)rawpos)[i]);
            ((u16*)outp)[5120000 + i] = f2bf(base + 0.5f * x);
        }
    }
}

extern "C" void kernel_launch(void* const* d_in, const int* in_sizes, int n_in,
                              void* d_out, int out_size, void* d_ws, size_t ws_size,
                              hipStream_t stream)
{
    // ws layout (bytes):
    //   [0,          10,240,000)  Ysu (bf16)
    //   [10,240,000, 20,480,000)  Ydu (bf16, +b1u folded)
    //   [20,480,000, 30,720,000)  Ysd
    //   [30,720,000, 40,960,000)  Ydd (+b1d)
    //   [40,960,000, 41,040,000)  cnt_up   (zeroed by prep)
    //   [41,040,000, 41,120,000)  cnt_dn   (zeroed by prep)
    //   [41,120,000, 41,200,000)  cur_up
    //   [41,200,000, 41,280,000)  cur_dn
    //   [41,280,000, 41,280,400)  bsum_up
    //   [41,280,400, 41,280,800)  bsum_dn
    //   [41,280,800, 42,080,800)  es_up
    //   [42,080,800, 42,880,800)  es_dn
    //   [42,880,800, 43,241,248)  weight fragments (180,224 u16)
    //   [43,241,248, 43,241,252)  flag
    //   [43,241,280, 64,201,280)  bf16-input fallback msg/pos acc (untouched when f32)
    u16*   Ysu     = (u16*)d_ws;
    u16*   Ydu     = (u16*)((char*)d_ws + 10240000);
    u16*   Ysd     = (u16*)((char*)d_ws + 20480000);
    u16*   Ydd     = (u16*)((char*)d_ws + 30720000);
    int*   cnt_up  = (int*)((char*)d_ws + 40960000);
    int*   cnt_dn  = (int*)((char*)d_ws + 41040000);
    int*   cur_up  = (int*)((char*)d_ws + 41120000);
    int*   cur_dn  = (int*)((char*)d_ws + 41200000);
    int*   bsum_up = (int*)((char*)d_ws + 41280000);
    int*   bsum_dn = (int*)((char*)d_ws + 41280400);
    int*   es_up   = (int*)((char*)d_ws + 41280800);
    int*   es_dn   = (int*)((char*)d_ws + 42080800);
    u16*   fbase   = (u16*)((char*)d_ws + 42880800);
    int*   flag    = (int*)((char*)d_ws + 43241248);
    float* ws_msg  = (float*)((char*)d_ws + 43241280);
    float* ws_pos  = (float*)((char*)d_ws + 63721280);
    if (ws_size < 43241252ULL) return;

    u16* f_m1u = fbase;              // 32768 (K=256)
    u16* f_m2u = fbase + 32768;
    u16* f_p1u = fbase + 49152;
    u16* f_m1d = fbase + 65536;
    u16* f_m2d = fbase + 98304;
    u16* f_p1d = fbase + 114688;
    u16* f_u1  = fbase + 131072;
    u16* f_u2  = fbase + 163840;

    const int* ei_up = (const int*)d_in[2];
    const int* ei_dn = (const int*)d_in[3];

    detect_kernel<<<1, 256, 0, stream>>>((const u16*)d_in[0], flag);

    prep_kernel<<<(5280000 + 255) / 256, 256, 0, stream>>>(d_out, ws_msg, ws_pos, cnt_up, flag);

    P8 wsf;
    wsf.w[0] = d_in[6];  wsf.w[1] = d_in[8];  wsf.w[2] = d_in[10]; wsf.w[3] = d_in[14];
    wsf.w[4] = d_in[16]; wsf.w[5] = d_in[18]; wsf.w[6] = d_in[22]; wsf.w[7] = d_in[24];
    make_frag_all<<<(FTOT + 255) / 256, 256, 0, stream>>>(wsf, fbase, flag);

    count2_kernel<<<(2 * EE + 255) / 256, 256, 0, stream>>>(ei_up, ei_dn, cnt_up, cnt_dn);
    SP sp;
    sp.cnt[0] = cnt_up; sp.cnt[1] = cnt_dn;
    sp.cur[0] = cur_up; sp.cur[1] = cur_dn;
    sp.bsum[0] = bsum_up; sp.bsum[1] = bsum_dn;
    scan1_kernel<<<2 * NBLK, 256, 0, stream>>>(sp);
    scan2_kernel<<<1, 256, 0, stream>>>(bsum_up, bsum_dn);
    scatter2_kernel<<<(2 * EE + 255) / 256, 256, 0, stream>>>(ei_up, ei_dn, cur_up, bsum_up,
                                                              cur_dn, bsum_dn, es_up, es_dn);

    nodey_kernel<<<625, 256, 0, stream>>>(d_in[0], f_m1u, f_m1d, d_in[7], d_in[15],
                                          Ysu, Ydu, Ysd, Ydd, flag);

    EP up, dn;
    up.eidx = ei_up; up.es = es_up; up.deg = d_in[4]; up.w1 = d_in[6];
    up.bias2 = d_in[9]; up.biasp1 = d_in[11]; up.wp2 = d_in[12]; up.biasp2 = d_in[13];
    up.fW2 = f_m2u; up.fP1 = f_p1u; up.Ys = Ysu; up.Yd = Ydu;
    dn.eidx = ei_dn; dn.es = es_dn; dn.deg = d_in[5]; dn.w1 = d_in[14];
    dn.bias2 = d_in[17]; dn.biasp1 = d_in[19]; dn.wp2 = d_in[20]; dn.biasp2 = d_in[21];
    dn.fW2 = f_m2d; dn.fP1 = f_p1d; dn.Ys = Ysd; dn.Yd = Ydd;

    edge_kernel<<<2 * BB * EBLK, 512, 0, stream>>>(d_in[1], up, dn, ws_msg, ws_pos, d_out, flag);

    update_kernel<<<625, 256, 0, stream>>>(d_in[0], d_in[1], f_u1, d_in[23], f_u2, d_in[25],
                                           d_out, ws_msg, ws_pos, flag);
}

// Round 8
// 553.576 us; speedup vs baseline: 1.0551x; 1.0551x over previous
//
#include <hip/hip_runtime.h>

#define BB 2
#define NN 20000
#define HH 128
#define EE 200000
#define EBLK 3125   // EE / 64
#define NBLK 79     // ceil(NN/256)

typedef unsigned short u16;
typedef __attribute__((ext_vector_type(4))) float f32x4;
typedef __bf16 bf16x8 __attribute__((ext_vector_type(8)));

#define MFMA(a, b, c) __builtin_amdgcn_mfma_f32_16x16x32_bf16((a), (b), (c), 0, 0, 0)

__device__ __forceinline__ float bf2f(u16 u) {
    union { unsigned int i; float f; } v; v.i = ((unsigned int)u) << 16; return v.f;
}
__device__ __forceinline__ u16 f2bf(float f) {
    union { __bf16 h; u16 u; } v; v.h = (__bf16)f; return v.u;
}
__device__ __forceinline__ float fastrcp(float x) {
    float r; asm volatile("v_rcp_f32 %0, %1" : "=v"(r) : "v"(x)); return r;
}
__device__ __forceinline__ float silu_f(float z) {
    return z * fastrcp(1.f + __expf(-z));
}
// flag-routed load: f32 raw or bf16 raw
__device__ __forceinline__ float ldv(const void* p, long i, int f) {
    return f ? ((const float*)p)[i] : bf2f(((const u16*)p)[i]);
}

// ---------------- dtype detection ----------------
__global__ void detect_kernel(const u16* __restrict__ f, int* __restrict__ flag) {
    int tid = threadIdx.x;
    u16 v = f[tid * 2];
    int e = (v >> 7) & 0xFF;
    int ok = (e >= 101 && e <= 143) ? 1 : 0;
    __shared__ int cnt;
    if (tid == 0) cnt = 0;
    __syncthreads();
    atomicAdd(&cnt, ok);
    __syncthreads();
    if (tid == 0) *flag = (cnt < 200) ? 1 : 0;   // 1 => inputs are float32
}

// ---------------- prep: zero accumulators (flag-routed) + CSR counters -----
__global__ __launch_bounds__(256) void prep_kernel(void* outp, float* __restrict__ ws_acc,
                                                   int* __restrict__ cnt,
                                                   const int* __restrict__ flag) {
    int i = blockIdx.x * 256 + threadIdx.x;
    if (i < 5240000) {
        if (*flag) ((float*)outp)[i] = 0.f;
        else ws_acc[i] = 0.f;              // ws_msg | ws_pos contiguous
    } else {
        int j = i - 5240000;
        if (j < 40000) cnt[j] = 0;         // cnt_up | cnt_dn contiguous
    }
}

// ---------------- canonicalize feat/pos/deg to bf16 ----------------
#define C4TOT 5280000
__global__ __launch_bounds__(256) void canon4_kernel(
    const void* __restrict__ f, const void* __restrict__ p,
    const void* __restrict__ du, const void* __restrict__ dd,
    u16* __restrict__ canon, const int* __restrict__ flag)
{
    int i = blockIdx.x * 256 + threadIdx.x;
    if (i >= C4TOT) return;
    int isf = *flag;
    const void* src; long j;
    if (i < 5120000)      { src = f;  j = i; }
    else if (i < 5240000) { src = p;  j = i - 5120000; }
    else if (i < 5260000) { src = du; j = i - 5240000; }
    else                  { src = dd; j = i - 5260000; }
    canon[i] = f2bf(ldv(src, j, isf));   // exact round-trip in bf16 case
}

// ---------------- weight fragment permutation (reads raw, flag-routed) -----
#define FTOT 180224
struct P8 { const void* w[8]; };

__global__ __launch_bounds__(256) void make_frag_all(P8 ws, u16* __restrict__ fbase,
                                                     const int* __restrict__ flag) {
    static const int foff[9] = { 0, 32768, 49152, 65536, 98304, 114688, 131072, 163840, 180224 };
    int i = blockIdx.x * 256 + threadIdx.x;
    if (i >= FTOT) return;
    int isf = *flag;
    int t = 0;
#pragma unroll 1
    while (i >= foff[t + 1]) ++t;
    int j = i - foff[t];
    int jj = j & 7, lane = (j >> 3) & 63, nt = (j >> 9) & 7, kt = j >> 12;
    int k = kt * 32 + ((lane >> 4) * 8) + jj;
    int n = nt * 16 + (lane & 15);
    fbase[i] = f2bf(ldv(ws.w[t], (long)k * 128 + n, isf));
}

// ---------------- CSR build ----------------
__global__ void count2_kernel(const int* __restrict__ eu, const int* __restrict__ ed,
                              int* __restrict__ cu, int* __restrict__ cd) {
    int e = blockIdx.x * 256 + threadIdx.x;
    if (e < EE) atomicAdd(&cu[eu[EE + e]], 1);
    else { e -= EE; if (e < EE) atomicAdd(&cd[ed[EE + e]], 1); }
}

struct SP { const int* cnt[2]; int* cur[2]; int* bsum[2]; };

__global__ __launch_bounds__(256) void scan1_kernel(SP p) {
    int half = blockIdx.x / NBLK;
    int b = blockIdx.x - half * NBLK;
    int t = threadIdx.x;
    int i = b * 256 + t;
    __shared__ int buf[256];
    int v = (i < NN) ? p.cnt[half][i] : 0;
    buf[t] = v;
    __syncthreads();
    for (int s = 1; s < 256; s <<= 1) {
        int x = (t >= s) ? buf[t - s] : 0;
        __syncthreads();
        buf[t] += x;
        __syncthreads();
    }
    if (i < NN) p.cur[half][i] = buf[t] - v;   // exclusive within block
    if (t == 255) p.bsum[half][b] = buf[255];
}

__global__ __launch_bounds__(256) void scan2_kernel(int* __restrict__ bu, int* __restrict__ bd) {
    __shared__ int buf[2][128];
    int half = threadIdx.x >> 7, t = threadIdx.x & 127;
    int* bs = half ? bd : bu;
    int v = (t < NBLK) ? bs[t] : 0;
    buf[half][t] = v;
    __syncthreads();
    for (int s = 1; s < 128; s <<= 1) {
        int x = (t >= s) ? buf[half][t - s] : 0;
        __syncthreads();
        buf[half][t] += x;
        __syncthreads();
    }
    if (t < NBLK) bs[t] = buf[half][t] - v;    // exclusive block offsets
}

// scatter with fused bsum add (scan3 folded in)
__global__ void scatter2_kernel(const int* __restrict__ eu, const int* __restrict__ ed,
                                int* __restrict__ cu, const int* __restrict__ bu,
                                int* __restrict__ cd, const int* __restrict__ bd,
                                int* __restrict__ su, int* __restrict__ sd) {
    int e = blockIdx.x * 256 + threadIdx.x;
    if (e < EE) {
        int d = eu[EE + e];
        int p = atomicAdd(&cu[d], 1) + bu[d >> 8];
        su[p] = e;
    } else {
        e -= EE;
        if (e < EE) {
            int d = ed[EE + e];
            int p = atomicAdd(&cd[d], 1) + bd[d >> 8];
            sd[p] = e;
        }
    }
}

// ---------------- edge kernel (round-6 structure, both halves in one grid) --
struct EP {
    const int* eidx; const int* es; const u16* deg;    // deg = canonical bf16
    const u16* fW1; const u16* fW2; const u16* fP1;    // MFMA frags
    const void* w1;                                    // raw w_msg1 (w1last = row 256)
    const void* bias1; const void* bias2; const void* biasp1;
    const void* wp2; const void* biasp2;               // raw, flag-routed
};

__global__ __launch_bounds__(512, 8) void edge_kernel(
    const u16* __restrict__ feat, const u16* __restrict__ posit,   // canonical bf16
    EP up, EP dn,
    float* __restrict__ ws_msg, float* __restrict__ ws_pos,
    void* __restrict__ outp, const int* __restrict__ flag)
{
    const int tid = threadIdx.x;
    const int lane = tid & 63;
    const int wv = tid >> 6;              // 0..7 = n-tile
    const int half = blockIdx.x / (BB * EBLK);
    const int rem = blockIdx.x - half * (BB * EBLK);
    const int bb = rem / EBLK;
    const int s0 = (rem - bb * EBLK) * 64;
    const EP P = half ? dn : up;
    const int isf = *flag;
    float* msg_acc = isf ? (float*)outp : ws_msg;
    float* pos_acc = isf ? (float*)outp + 5120000 : ws_pos;

    __shared__ u16 sX[64][136];   // h_src -> msg-hidden -> pos-hidden
    __shared__ u16 sY[64][136];   // h_dst -> messages
    __shared__ float sRel[64][3];
    __shared__ float sDist[64];
    __shared__ float sInv[64];
    __shared__ int sSrc[64], sDst[64];

    if (tid < 64) {
        int e = P.es[s0 + tid];
        int s = P.eidx[e];
        int d = P.eidx[EE + e];
        sSrc[tid] = s; sDst[tid] = d;
        sInv[tid] = 1.f / fmaxf(bf2f(P.deg[d]), 1.f);
        const u16* ps = posit + ((size_t)bb * NN + s) * 3;
        const u16* pd = posit + ((size_t)bb * NN + d) * 3;
        float dx = bf2f(ps[0]) - bf2f(pd[0]);
        float dy = bf2f(ps[1]) - bf2f(pd[1]);
        float dz = bf2f(ps[2]) - bf2f(pd[2]);
        sRel[tid][0] = dx; sRel[tid][1] = dy; sRel[tid][2] = dz;
        sDist[tid] = sqrtf(dx * dx + dy * dy + dz * dz);
    }
    __syncthreads();   // B0

    // gather h_src -> sX, h_dst -> sY (8 threads/row, 32B each)
    {
        const int r = tid >> 3, part = tid & 7;
        const uint4* fs = (const uint4*)(feat + ((size_t)bb * NN + sSrc[r]) * HH);
        const uint4* fd = (const uint4*)(feat + ((size_t)bb * NN + sDst[r]) * HH);
        uint4* as = (uint4*)&sX[r][part * 16];
        uint4* ad = (uint4*)&sY[r][part * 16];
#pragma unroll
        for (int i = 0; i < 2; ++i) { as[i] = fs[part * 2 + i]; ad[i] = fd[part * 2 + i]; }
    }
    __syncthreads();   // B1

    const int nt = wv;
    const int mrow = lane & 15;
    const int kq = (lane >> 4) * 8;
    const int crow = (lane >> 4) * 4;
    const int ccol = lane & 15;
    const int col = nt * 16 + ccol;

    f32x4 acc[4];
#pragma unroll
    for (int mt = 0; mt < 4; ++mt) acc[mt] = (f32x4){0.f, 0.f, 0.f, 0.f};

    // ----- msg layer 1 : [h_src | h_dst] @ W1[0:256]  (K=256) -----
#pragma unroll
    for (int kt = 0; kt < 8; ++kt) {
        const u16* Xb = (kt < 4) ? &sX[0][0] : &sY[0][0];
        const int kk = (kt & 3) * 32 + kq;
        bf16x8 bw = *(const bf16x8*)(P.fW1 + (size_t)(((kt * 8 + nt) * 64 + lane) * 8));
#pragma unroll
        for (int mt = 0; mt < 4; ++mt) {
            bf16x8 a = *(const bf16x8*)(Xb + (mt * 16 + mrow) * 136 + kk);
            acc[mt] = MFMA(a, bw, acc[mt]);
        }
    }
    __syncthreads();   // B2: all L1 reads of sX/sY done

    // epilogue: + dist*W1[256] + b1, silu -> sX
    {
        const float wl = ldv(P.w1, 32768 + col, isf);
        const float bb2 = ldv(P.bias1, col, isf);
#pragma unroll
        for (int mt = 0; mt < 4; ++mt) {
#pragma unroll
            for (int r = 0; r < 4; ++r) {
                const int row = mt * 16 + crow + r;
                float z = fmaf(sDist[row], wl, acc[mt][r]) + bb2;
                sX[row][col] = f2bf(silu_f(z));
            }
        }
    }
    __syncthreads();   // B3

    // ----- msg layer 2 : sX @ W2 + b2 = messages -> sY (K=128) -----
#pragma unroll
    for (int mt = 0; mt < 4; ++mt) acc[mt] = (f32x4){0.f, 0.f, 0.f, 0.f};
#pragma unroll
    for (int kt = 0; kt < 4; ++kt) {
        const int kk = kt * 32 + kq;
        bf16x8 bw = *(const bf16x8*)(P.fW2 + (size_t)(((kt * 8 + nt) * 64 + lane) * 8));
#pragma unroll
        for (int mt = 0; mt < 4; ++mt) {
            bf16x8 a = *(const bf16x8*)(&sX[0][0] + (mt * 16 + mrow) * 136 + kk);
            acc[mt] = MFMA(a, bw, acc[mt]);
        }
    }
    {
        const float bb2 = ldv(P.bias2, col, isf);
#pragma unroll
        for (int mt = 0; mt < 4; ++mt) {
#pragma unroll
            for (int r = 0; r < 4; ++r) {
                const int row = mt * 16 + crow + r;
                sY[row][col] = f2bf(acc[mt][r] + bb2);
            }
        }
    }
    __syncthreads();   // B4: messages visible; all reads of sX done

    // ----- pos layer 1 : silu(messages @ P1 + bp1) -> sX (K=128) -----
#pragma unroll
    for (int mt = 0; mt < 4; ++mt) acc[mt] = (f32x4){0.f, 0.f, 0.f, 0.f};
#pragma unroll
    for (int kt = 0; kt < 4; ++kt) {
        const int kk = kt * 32 + kq;
        bf16x8 bw = *(const bf16x8*)(P.fP1 + (size_t)(((kt * 8 + nt) * 64 + lane) * 8));
#pragma unroll
        for (int mt = 0; mt < 4; ++mt) {
            bf16x8 a = *(const bf16x8*)(&sY[0][0] + (mt * 16 + mrow) * 136 + kk);
            acc[mt] = MFMA(a, bw, acc[mt]);
        }
    }

    // segment-reduced scatter of messages (rows sorted by dst):
    // 512 threads = 128 cols x 4 row-spans of 16, pre-scaled by 1/clip(deg)
    {
        const int scol = tid & 127;
        const int r0 = (tid >> 7) * 16;
        float accv = 0.f;
        int dprev = sDst[r0];
        float invprev = sInv[r0];
#pragma unroll 1
        for (int r = r0; r < r0 + 16; ++r) {
            int dcur = sDst[r];
            if (dcur != dprev) {
                unsafeAtomicAdd(&msg_acc[((size_t)bb * NN + dprev) * HH + scol], accv * invprev);
                accv = 0.f; dprev = dcur; invprev = sInv[r];
            }
            accv += bf2f(sY[r][scol]);
        }
        unsafeAtomicAdd(&msg_acc[((size_t)bb * NN + dprev) * HH + scol], accv * invprev);
    }

    // pos1 epilogue -> sX
    {
        const float bb2 = ldv(P.biasp1, col, isf);
#pragma unroll
        for (int mt = 0; mt < 4; ++mt) {
#pragma unroll
            for (int r = 0; r < 4; ++r) {
                const int row = mt * 16 + crow + r;
                sX[row][col] = f2bf(silu_f(acc[mt][r] + bb2));
            }
        }
    }
    __syncthreads();   // B5

    // ----- pos layer 2 : tanh(hidden @ p2 + bp2) ; scatter wgt*rel_pos -----
    {
        const int r = tid >> 3, q = tid & 7;
        const unsigned* t32 = (const unsigned*)&sX[r][q * 16];
        float p = 0.f;
#pragma unroll
        for (int k = 0; k < 8; ++k) {
            unsigned a = t32[k];
            float w0 = ldv(P.wp2, q * 16 + 2 * k, isf);
            float w1 = ldv(P.wp2, q * 16 + 2 * k + 1, isf);
            p = fmaf(bf2f((u16)(a & 0xffff)), w0, p);
            p = fmaf(bf2f((u16)(a >> 16)), w1, p);
        }
        p += __shfl_xor(p, 1);
        p += __shfl_xor(p, 2);
        p += __shfl_xor(p, 4);
        if (q == 0) {
            float wgt = tanhf(p + ldv(P.biasp2, 0, isf));
            const size_t pb = ((size_t)bb * NN + sDst[r]) * 3;
            unsafeAtomicAdd(&pos_acc[pb + 0], wgt * sRel[r][0]);
            unsafeAtomicAdd(&pos_acc[pb + 1], wgt * sRel[r][1]);
            unsafeAtomicAdd(&pos_acc[pb + 2], wgt * sRel[r][2]);
        }
    }
}

// ---------------- update + fused pos output ----------------
__global__ __launch_bounds__(256) void update_kernel(
    const void* __restrict__ rawfeat, const void* __restrict__ rawpos,
    const u16* __restrict__ fU1, const void* __restrict__ bu1,
    const u16* __restrict__ fU2, const void* __restrict__ bu2,
    void* __restrict__ outp, float* __restrict__ ws_msg, float* __restrict__ ws_pos,
    const int* __restrict__ flag)
{
    const int tid = threadIdx.x;
    const int lane = tid & 63;
    const int wv = tid >> 6;
    const int row0 = blockIdx.x * 64;
    const int isf = *flag;
    const float* magg = isf ? (const float*)outp : ws_msg;
    const float* pacc = isf ? (const float*)outp + 5120000 : ws_pos;

    __shared__ u16 sA[64][136];   // features (bf16)
    __shared__ u16 sB[64][136];   // msg_acc -> hidden (reused)

    if (isf) {
        const float* fp = (const float*)rawfeat + (size_t)row0 * HH;
        for (int i = tid; i < 1024; i += 256) {
            int r = i >> 4, c = (i & 15) * 8;
            float4 v0 = *(const float4*)(fp + (size_t)r * HH + c);
            float4 v1 = *(const float4*)(fp + (size_t)r * HH + c + 4);
            uint4 o;
            o.x = (unsigned)f2bf(v0.x) | ((unsigned)f2bf(v0.y) << 16);
            o.y = (unsigned)f2bf(v0.z) | ((unsigned)f2bf(v0.w) << 16);
            o.z = (unsigned)f2bf(v1.x) | ((unsigned)f2bf(v1.y) << 16);
            o.w = (unsigned)f2bf(v1.z) | ((unsigned)f2bf(v1.w) << 16);
            *(uint4*)&sA[r][c] = o;
        }
    } else {
        const uint4* fp = (const uint4*)((const u16*)rawfeat + (size_t)row0 * HH);
        for (int i = tid; i < 1024; i += 256) {
            int r = i >> 4, c = i & 15;
            *(uint4*)&sA[r][c * 8] = fp[i];
        }
    }
    {
        const float4* am = (const float4*)(magg) + (size_t)row0 * 32;
        for (int i = tid; i < 2048; i += 256) {
            int r = i >> 5;
            float4 v = am[i];
            int c = (i & 31) * 4;
            sB[r][c + 0] = f2bf(v.x);
            sB[r][c + 1] = f2bf(v.y);
            sB[r][c + 2] = f2bf(v.z);
            sB[r][c + 3] = f2bf(v.w);
        }
    }
    __syncthreads();

    const int nt0 = wv * 2;
    const int mrow = lane & 15;
    const int kq = (lane >> 4) * 8;
    const int crow = (lane >> 4) * 4;
    const int ccol = lane & 15;

    f32x4 acc[4][2];
#pragma unroll
    for (int mt = 0; mt < 4; ++mt) {
        acc[mt][0] = (f32x4){0.f, 0.f, 0.f, 0.f};
        acc[mt][1] = (f32x4){0.f, 0.f, 0.f, 0.f};
    }
#pragma unroll
    for (int kt = 0; kt < 8; ++kt) {
        const u16* Xb = (kt < 4) ? &sA[0][0] : &sB[0][0];
        const int kk = (kt & 3) * 32 + kq;
        bf16x8 bw0 = *(const bf16x8*)(fU1 + (size_t)(((kt * 8 + nt0) * 64 + lane) * 8));
        bf16x8 bw1 = *(const bf16x8*)(fU1 + (size_t)(((kt * 8 + nt0 + 1) * 64 + lane) * 8));
#pragma unroll
        for (int mt = 0; mt < 4; ++mt) {
            bf16x8 a = *(const bf16x8*)(Xb + (mt * 16 + mrow) * 136 + kk);
            acc[mt][0] = MFMA(a, bw0, acc[mt][0]);
            acc[mt][1] = MFMA(a, bw1, acc[mt][1]);
        }
    }
    __syncthreads();

#pragma unroll
    for (int mt = 0; mt < 4; ++mt) {
#pragma unroll
        for (int n2 = 0; n2 < 2; ++n2) {
            const int col = (nt0 + n2) * 16 + ccol;
            const float bb = ldv(bu1, col, isf);
#pragma unroll
            for (int r = 0; r < 4; ++r) {
                const int row = mt * 16 + crow + r;
                sB[row][col] = f2bf(silu_f(acc[mt][n2][r] + bb));
            }
        }
    }
    __syncthreads();

#pragma unroll
    for (int mt = 0; mt < 4; ++mt) {
        acc[mt][0] = (f32x4){0.f, 0.f, 0.f, 0.f};
        acc[mt][1] = (f32x4){0.f, 0.f, 0.f, 0.f};
    }
#pragma unroll
    for (int kt = 0; kt < 4; ++kt) {
        const int kk = kt * 32 + kq;
        bf16x8 bw0 = *(const bf16x8*)(fU2 + (size_t)(((kt * 8 + nt0) * 64 + lane) * 8));
        bf16x8 bw1 = *(const bf16x8*)(fU2 + (size_t)(((kt * 8 + nt0 + 1) * 64 + lane) * 8));
#pragma unroll
        for (int mt = 0; mt < 4; ++mt) {
            bf16x8 a = *(const bf16x8*)(&sB[0][0] + (mt * 16 + mrow) * 136 + kk);
            acc[mt][0] = MFMA(a, bw0, acc[mt][0]);
            acc[mt][1] = MFMA(a, bw1, acc[mt][1]);
        }
    }
#pragma unroll
    for (int mt = 0; mt < 4; ++mt) {
#pragma unroll
        for (int n2 = 0; n2 < 2; ++n2) {
            const int col = (nt0 + n2) * 16 + ccol;
            const float bb = ldv(bu2, col, isf);
#pragma unroll
            for (int r = 0; r < 4; ++r) {
                const int row = mt * 16 + crow + r;
                const size_t idx = (size_t)(row0 + row) * HH + col;
                if (isf) {
                    float base = ((const float*)rawfeat)[idx];
                    ((float*)outp)[idx] = acc[mt][n2][r] + bb + base;
                } else {
                    float base = bf2f(sA[row][col]);
                    ((u16*)outp)[idx] = f2bf(acc[mt][n2][r] + bb + base);
                }
            }
        }
    }

    // fused positions output: 3 elems per node row (192 per block)
    if (tid < 192) {
        int i = row0 * 3 + tid;
        float x = pacc[i];
        if (isf) {
            float base = ((const float*)rawpos)[i];
            ((float*)outp)[5120000 + i] = base + 0.5f * x;
        } else {
            float base = bf2f(((const u16*)rawpos)[i]);
            ((u16*)outp)[5120000 + i] = f2bf(base + 0.5f * x);
        }
    }
}

extern "C" void kernel_launch(void* const* d_in, const int* in_sizes, int n_in,
                              void* d_out, int out_size, void* d_ws, size_t ws_size,
                              hipStream_t stream)
{
    // ws layout (bytes):
    //   [0,          20,480,000)  ws_msg f32 (bf16-input fallback; zeroed by prep)
    //   [20,480,000, 20,960,000)  ws_pos f32
    //   [20,960,000, 21,040,000)  cnt_up   (zeroed by prep)
    //   [21,040,000, 21,120,000)  cnt_dn
    //   [21,120,000, 21,200,000)  cur_up
    //   [21,200,000, 21,280,000)  cur_dn
    //   [21,280,000, 21,280,400)  bsum_up
    //   [21,280,400, 21,280,800)  bsum_dn
    //   [21,280,800, 22,080,800)  es_up
    //   [22,080,800, 22,880,800)  es_dn
    //   [22,880,800, 23,241,248)  weight fragments (180,224 u16)
    //   [23,241,248, 33,801,248)  canonical bf16 feat/pos/deg (5,280,000 u16)
    //   [33,801,248, +4)          flag
    float* ws_msg  = (float*)d_ws;
    float* ws_pos  = (float*)((char*)d_ws + 20480000);
    int*   cnt_up  = (int*)((char*)d_ws + 20960000);
    int*   cnt_dn  = (int*)((char*)d_ws + 21040000);
    int*   cur_up  = (int*)((char*)d_ws + 21120000);
    int*   cur_dn  = (int*)((char*)d_ws + 21200000);
    int*   bsum_up = (int*)((char*)d_ws + 21280000);
    int*   bsum_dn = (int*)((char*)d_ws + 21280400);
    int*   es_up   = (int*)((char*)d_ws + 21280800);
    int*   es_dn   = (int*)((char*)d_ws + 22080800);
    u16*   fbase   = (u16*)((char*)d_ws + 22880800);
    u16*   canon   = (u16*)((char*)d_ws + 23241248);
    int*   flag    = (int*)((char*)d_ws + 33801248);
    if (ws_size < 33801252ULL) return;

    u16* f_m1u = fbase;              // 32768 (K=256)
    u16* f_m2u = fbase + 32768;
    u16* f_p1u = fbase + 49152;
    u16* f_m1d = fbase + 65536;
    u16* f_m2d = fbase + 98304;
    u16* f_p1d = fbase + 114688;
    u16* f_u1  = fbase + 131072;
    u16* f_u2  = fbase + 163840;

    u16* cfeat = canon;
    u16* cpos  = canon + 5120000;
    u16* cdgu  = canon + 5240000;
    u16* cdgd  = canon + 5260000;

    const int* ei_up = (const int*)d_in[2];
    const int* ei_dn = (const int*)d_in[3];

    detect_kernel<<<1, 256, 0, stream>>>((const u16*)d_in[0], flag);

    prep_kernel<<<(5280000 + 255) / 256, 256, 0, stream>>>(d_out, ws_msg, cnt_up, flag);

    canon4_kernel<<<(C4TOT + 255) / 256, 256, 0, stream>>>(d_in[0], d_in[1], d_in[4], d_in[5],
                                                           canon, flag);

    P8 wsf;
    wsf.w[0] = d_in[6];  wsf.w[1] = d_in[8];  wsf.w[2] = d_in[10]; wsf.w[3] = d_in[14];
    wsf.w[4] = d_in[16]; wsf.w[5] = d_in[18]; wsf.w[6] = d_in[22]; wsf.w[7] = d_in[24];
    make_frag_all<<<(FTOT + 255) / 256, 256, 0, stream>>>(wsf, fbase, flag);

    count2_kernel<<<(2 * EE + 255) / 256, 256, 0, stream>>>(ei_up, ei_dn, cnt_up, cnt_dn);
    SP sp;
    sp.cnt[0] = cnt_up; sp.cnt[1] = cnt_dn;
    sp.cur[0] = cur_up; sp.cur[1] = cur_dn;
    sp.bsum[0] = bsum_up; sp.bsum[1] = bsum_dn;
    scan1_kernel<<<2 * NBLK, 256, 0, stream>>>(sp);
    scan2_kernel<<<1, 256, 0, stream>>>(bsum_up, bsum_dn);
    scatter2_kernel<<<(2 * EE + 255) / 256, 256, 0, stream>>>(ei_up, ei_dn, cur_up, bsum_up,
                                                              cur_dn, bsum_dn, es_up, es_dn);

    EP up, dn;
    up.eidx = ei_up; up.es = es_up; up.deg = cdgu;
    up.fW1 = f_m1u; up.fW2 = f_m2u; up.fP1 = f_p1u;
    up.w1 = d_in[6]; up.bias1 = d_in[7]; up.bias2 = d_in[9];
    up.biasp1 = d_in[11]; up.wp2 = d_in[12]; up.biasp2 = d_in[13];
    dn.eidx = ei_dn; dn.es = es_dn; dn.deg = cdgd;
    dn.fW1 = f_m1d; dn.fW2 = f_m2d; dn.fP1 = f_p1d;
    dn.w1 = d_in[14]; dn.bias1 = d_in[15]; dn.bias2 = d_in[17];
    dn.biasp1 = d_in[19]; dn.wp2 = d_in[20]; dn.biasp2 = d_in[21];

    edge_kernel<<<2 * BB * EBLK, 512, 0, stream>>>(cfeat, cpos, up, dn, ws_msg, ws_pos,
                                                   d_out, flag);

    update_kernel<<<625, 256, 0, stream>>>(d_in[0], d_in[1], f_u1, d_in[23], f_u2, d_in[25],
                                           d_out, ws_msg, ws_pos, flag);
}

// Round 9
// 526.160 us; speedup vs baseline: 1.1101x; 1.0521x over previous
//
#include <hip/hip_runtime.h>

#define BB 2
#define NN 20000
#define HH 128
#define EE 200000
#define EBLK 3125   // EE / 64
#define NBLK 79     // ceil(NN/256)

typedef unsigned short u16;
typedef __attribute__((ext_vector_type(4))) float f32x4;
typedef __bf16 bf16x8 __attribute__((ext_vector_type(8)));

#define MFMA(a, b, c) __builtin_amdgcn_mfma_f32_16x16x32_bf16((a), (b), (c), 0, 0, 0)

__device__ __forceinline__ float bf2f(u16 u) {
    union { unsigned int i; float f; } v; v.i = ((unsigned int)u) << 16; return v.f;
}
__device__ __forceinline__ u16 f2bf(float f) {
    union { __bf16 h; u16 u; } v; v.h = (__bf16)f; return v.u;
}
#if __has_builtin(__builtin_amdgcn_rcpf)
__device__ __forceinline__ float rcpf(float x) { return __builtin_amdgcn_rcpf(x); }
#else
__device__ __forceinline__ float rcpf(float x) { return 1.f / x; }
#endif
__device__ __forceinline__ float silu_f(float z) { return z * rcpf(1.f + __expf(-z)); }
// flag-routed load (aux kernels only): f32 raw or bf16 raw
__device__ __forceinline__ float ldv(const void* p, long i, int f) {
    return f ? ((const float*)p)[i] : bf2f(((const u16*)p)[i]);
}

// ---------------- dtype detection ----------------
__global__ void detect_kernel(const u16* __restrict__ f, int* __restrict__ flag) {
    int tid = threadIdx.x;
    u16 v = f[tid * 2];
    int e = (v >> 7) & 0xFF;
    int ok = (e >= 101 && e <= 143) ? 1 : 0;
    __shared__ int cnt;
    if (tid == 0) cnt = 0;
    __syncthreads();
    atomicAdd(&cnt, ok);
    __syncthreads();
    if (tid == 0) *flag = (cnt < 200) ? 1 : 0;   // 1 => inputs are float32
}

// ---------------- prep: zero ws accumulators + CSR counters ----------------
__global__ __launch_bounds__(256) void prep_kernel(float* __restrict__ ws_acc,
                                                   int* __restrict__ cnt) {
    int i = blockIdx.x * 256 + threadIdx.x;
    if (i < 5240000) ws_acc[i] = 0.f;     // ws_msg | ws_pos contiguous
    else { int j = i - 5240000; if (j < 40000) cnt[j] = 0; }
}

// ---------------- canonicalize feat/pos/deg + small weights to bf16 --------
#define C5TOT 5281540
struct P18 { const void* p[18]; };

__global__ __launch_bounds__(256) void canon5_kernel(P18 ptrs, u16* __restrict__ canon,
                                                     const int* __restrict__ flag)
{
    static const int off[19] = {
        0, 5120000, 5240000, 5260000, 5280000,
        5280128, 5280256, 5280384, 5280512, 5280640,
        5280642, 5280770, 5280898, 5281026, 5281154, 5281282,
        5281284, 5281412, 5281540 };
    static const int rsz[18] = {
        5120000, 120000, 20000, 20000,
        128, 128, 128, 128, 128, 1,
        128, 128, 128, 128, 128, 1,
        128, 128 };
    static const int soff[18] = {
        0, 0, 0, 0,
        32768, 0, 0, 0, 0, 0,
        32768, 0, 0, 0, 0, 0,
        0, 0 };
    int i = blockIdx.x * 256 + threadIdx.x;
    if (i >= C5TOT) return;
    int isf = *flag;
    int t = 0;
#pragma unroll 1
    while (i >= off[t + 1]) ++t;
    int j = i - off[t];
    u16 v = 0;
    if (j < rsz[t]) v = f2bf(ldv(ptrs.p[t], (long)soff[t] + j, isf));
    canon[i] = v;
}

// ---------------- weight fragment permutation (reads raw, flag-routed) -----
#define FTOT 180224
struct P8 { const void* w[8]; };

__global__ __launch_bounds__(256) void make_frag_all(P8 ws, u16* __restrict__ fbase,
                                                     const int* __restrict__ flag) {
    static const int foff[9] = { 0, 32768, 49152, 65536, 98304, 114688, 131072, 163840, 180224 };
    int i = blockIdx.x * 256 + threadIdx.x;
    if (i >= FTOT) return;
    int isf = *flag;
    int t = 0;
#pragma unroll 1
    while (i >= foff[t + 1]) ++t;
    int j = i - foff[t];
    int jj = j & 7, lane = (j >> 3) & 63, nt = (j >> 9) & 7, kt = j >> 12;
    int k = kt * 32 + ((lane >> 4) * 8) + jj;
    int n = nt * 16 + (lane & 15);
    fbase[i] = f2bf(ldv(ws.w[t], (long)k * 128 + n, isf));
}

// ---------------- CSR build ----------------
__global__ void count2_kernel(const int* __restrict__ eu, const int* __restrict__ ed,
                              int* __restrict__ cu, int* __restrict__ cd) {
    int e = blockIdx.x * 256 + threadIdx.x;
    if (e < EE) atomicAdd(&cu[eu[EE + e]], 1);
    else { e -= EE; if (e < EE) atomicAdd(&cd[ed[EE + e]], 1); }
}

struct SP { const int* cnt[2]; int* cur[2]; int* bsum[2]; };

__global__ __launch_bounds__(256) void scan1_kernel(SP p) {
    int half = blockIdx.x / NBLK;
    int b = blockIdx.x - half * NBLK;
    int t = threadIdx.x;
    int i = b * 256 + t;
    __shared__ int buf[256];
    int v = (i < NN) ? p.cnt[half][i] : 0;
    buf[t] = v;
    __syncthreads();
    for (int s = 1; s < 256; s <<= 1) {
        int x = (t >= s) ? buf[t - s] : 0;
        __syncthreads();
        buf[t] += x;
        __syncthreads();
    }
    if (i < NN) p.cur[half][i] = buf[t] - v;   // exclusive within block
    if (t == 255) p.bsum[half][b] = buf[255];
}

__global__ __launch_bounds__(256) void scan2_kernel(int* __restrict__ bu, int* __restrict__ bd) {
    __shared__ int buf[2][128];
    int half = threadIdx.x >> 7, t = threadIdx.x & 127;
    int* bs = half ? bd : bu;
    int v = (t < NBLK) ? bs[t] : 0;
    buf[half][t] = v;
    __syncthreads();
    for (int s = 1; s < 128; s <<= 1) {
        int x = (t >= s) ? buf[half][t - s] : 0;
        __syncthreads();
        buf[half][t] += x;
        __syncthreads();
    }
    if (t < NBLK) bs[t] = buf[half][t] - v;    // exclusive block offsets
}

// scatter with fused bsum add
__global__ void scatter2_kernel(const int* __restrict__ eu, const int* __restrict__ ed,
                                int* __restrict__ cu, const int* __restrict__ bu,
                                int* __restrict__ cd, const int* __restrict__ bd,
                                int* __restrict__ su, int* __restrict__ sd) {
    int e = blockIdx.x * 256 + threadIdx.x;
    if (e < EE) {
        int d = eu[EE + e];
        int p = atomicAdd(&cu[d], 1) + bu[d >> 8];
        su[p] = e;
    } else {
        e -= EE;
        if (e < EE) {
            int d = ed[EE + e];
            int p = atomicAdd(&cd[d], 1) + bd[d >> 8];
            sd[p] = e;
        }
    }
}

// ---------------- edge kernel (r6 structure; all small weights canonical) --
struct EP {
    const int* eidx; const int* es; const u16* deg;
    const u16* fW1; const u16* fW2; const u16* fP1;
    const u16* w1last; const u16* bias1; const u16* bias2;
    const u16* biasp1; const u16* wp2; const u16* biasp2;
};

__global__ __launch_bounds__(512, 8) void edge_kernel(
    const u16* __restrict__ feat, const u16* __restrict__ posit,   // canonical bf16
    EP up, EP dn,
    float* __restrict__ msg_base, float* __restrict__ pos_base)
{
    const int tid = threadIdx.x;
    const int lane = tid & 63;
    const int wv = tid >> 6;              // 0..7 = n-tile
    const int half = blockIdx.x / (BB * EBLK);
    const int rem = blockIdx.x - half * (BB * EBLK);
    const int bb = rem / EBLK;
    const int s0 = (rem - bb * EBLK) * 64;
    const EP P = half ? dn : up;
    float* msg_acc = msg_base + (size_t)bb * NN * HH;
    float* pos_acc = pos_base + (size_t)bb * NN * 3;

    __shared__ u16 sX[64][136];   // h_src -> msg-hidden -> pos-hidden
    __shared__ u16 sY[64][136];   // h_dst -> messages
    __shared__ float sRel[64][3];
    __shared__ float sDist[64];
    __shared__ float sInv[64];
    __shared__ int sDst[64];

    // meta (no barrier needed before gather: consumed only after B2/B4/B5)
    if (tid < 64) {
        int e = P.es[s0 + tid];
        int s = P.eidx[e];
        int d = P.eidx[EE + e];
        sDst[tid] = d;
        sInv[tid] = 1.f / fmaxf(bf2f(P.deg[d]), 1.f);
        const u16* ps = posit + ((size_t)bb * NN + s) * 3;
        const u16* pd = posit + ((size_t)bb * NN + d) * 3;
        float dx = bf2f(ps[0]) - bf2f(pd[0]);
        float dy = bf2f(ps[1]) - bf2f(pd[1]);
        float dz = bf2f(ps[2]) - bf2f(pd[2]);
        sRel[tid][0] = dx; sRel[tid][1] = dy; sRel[tid][2] = dz;
        sDist[tid] = sqrtf(dx * dx + dy * dy + dz * dz);
    }

    // gather h_src -> sX, h_dst -> sY; each thread fetches its own indices
    // (8 threads/row read identical es/eidx addresses -> L1 broadcast)
    {
        const int r = tid >> 3, part = tid & 7;
        int e = P.es[s0 + r];
        int s = P.eidx[e];
        int d = P.eidx[EE + e];
        const uint4* fs = (const uint4*)(feat + ((size_t)bb * NN + s) * HH);
        const uint4* fd = (const uint4*)(feat + ((size_t)bb * NN + d) * HH);
        uint4* as = (uint4*)&sX[r][part * 16];
        uint4* ad = (uint4*)&sY[r][part * 16];
#pragma unroll
        for (int i = 0; i < 2; ++i) { as[i] = fs[part * 2 + i]; ad[i] = fd[part * 2 + i]; }
    }
    __syncthreads();   // B1

    const int nt = wv;
    const int mrow = lane & 15;
    const int kq = (lane >> 4) * 8;
    const int crow = (lane >> 4) * 4;
    const int ccol = lane & 15;
    const int col = nt * 16 + ccol;

    f32x4 acc[4];
#pragma unroll
    for (int mt = 0; mt < 4; ++mt) acc[mt] = (f32x4){0.f, 0.f, 0.f, 0.f};

    // ----- msg layer 1 : [h_src | h_dst] @ W1[0:256]  (K=256) -----
#pragma unroll
    for (int kt = 0; kt < 8; ++kt) {
        const u16* Xb = (kt < 4) ? &sX[0][0] : &sY[0][0];
        const int kk = (kt & 3) * 32 + kq;
        bf16x8 bw = *(const bf16x8*)(P.fW1 + (size_t)(((kt * 8 + nt) * 64 + lane) * 8));
#pragma unroll
        for (int mt = 0; mt < 4; ++mt) {
            bf16x8 a = *(const bf16x8*)(Xb + (mt * 16 + mrow) * 136 + kk);
            acc[mt] = MFMA(a, bw, acc[mt]);
        }
    }
    __syncthreads();   // B2: all L1 reads of sX/sY done

    // epilogue: + dist*W1[256] + b1, silu -> sX
    {
        const float wl = bf2f(P.w1last[col]);
        const float bb2 = bf2f(P.bias1[col]);
#pragma unroll
        for (int mt = 0; mt < 4; ++mt) {
#pragma unroll
            for (int r = 0; r < 4; ++r) {
                const int row = mt * 16 + crow + r;
                float z = fmaf(sDist[row], wl, acc[mt][r]) + bb2;
                sX[row][col] = f2bf(silu_f(z));
            }
        }
    }
    __syncthreads();   // B3

    // ----- msg layer 2 : sX @ W2 + b2 = messages -> sY (K=128) -----
#pragma unroll
    for (int mt = 0; mt < 4; ++mt) acc[mt] = (f32x4){0.f, 0.f, 0.f, 0.f};
#pragma unroll
    for (int kt = 0; kt < 4; ++kt) {
        const int kk = kt * 32 + kq;
        bf16x8 bw = *(const bf16x8*)(P.fW2 + (size_t)(((kt * 8 + nt) * 64 + lane) * 8));
#pragma unroll
        for (int mt = 0; mt < 4; ++mt) {
            bf16x8 a = *(const bf16x8*)(&sX[0][0] + (mt * 16 + mrow) * 136 + kk);
            acc[mt] = MFMA(a, bw, acc[mt]);
        }
    }
    {
        const float bb2 = bf2f(P.bias2[col]);
#pragma unroll
        for (int mt = 0; mt < 4; ++mt) {
#pragma unroll
            for (int r = 0; r < 4; ++r) {
                const int row = mt * 16 + crow + r;
                sY[row][col] = f2bf(acc[mt][r] + bb2);
            }
        }
    }
    __syncthreads();   // B4: messages visible; all reads of sX done

    // ----- pos layer 1 : silu(messages @ P1 + bp1) -> sX (K=128) -----
#pragma unroll
    for (int mt = 0; mt < 4; ++mt) acc[mt] = (f32x4){0.f, 0.f, 0.f, 0.f};
#pragma unroll
    for (int kt = 0; kt < 4; ++kt) {
        const int kk = kt * 32 + kq;
        bf16x8 bw = *(const bf16x8*)(P.fP1 + (size_t)(((kt * 8 + nt) * 64 + lane) * 8));
#pragma unroll
        for (int mt = 0; mt < 4; ++mt) {
            bf16x8 a = *(const bf16x8*)(&sY[0][0] + (mt * 16 + mrow) * 136 + kk);
            acc[mt] = MFMA(a, bw, acc[mt]);
        }
    }

    // segment-reduced scatter of messages (rows sorted by dst):
    // 512 threads = 128 cols x 4 row-spans of 16, pre-scaled by 1/clip(deg)
    {
        const int scol = tid & 127;
        const int r0 = (tid >> 7) * 16;
        float accv = 0.f;
        int dprev = sDst[r0];
        float invprev = sInv[r0];
#pragma unroll 1
        for (int r = r0; r < r0 + 16; ++r) {
            int dcur = sDst[r];
            if (dcur != dprev) {
                unsafeAtomicAdd(&msg_acc[(size_t)dprev * HH + scol], accv * invprev);
                accv = 0.f; dprev = dcur; invprev = sInv[r];
            }
            accv += bf2f(sY[r][scol]);
        }
        unsafeAtomicAdd(&msg_acc[(size_t)dprev * HH + scol], accv * invprev);
    }

    // pos1 epilogue -> sX
    {
        const float bb2 = bf2f(P.biasp1[col]);
#pragma unroll
        for (int mt = 0; mt < 4; ++mt) {
#pragma unroll
            for (int r = 0; r < 4; ++r) {
                const int row = mt * 16 + crow + r;
                sX[row][col] = f2bf(silu_f(acc[mt][r] + bb2));
            }
        }
    }
    __syncthreads();   // B5

    // ----- pos layer 2 : tanh(hidden @ p2 + bp2) ; scatter wgt*rel_pos -----
    {
        const int r = tid >> 3, q = tid & 7;
        const unsigned* t32 = (const unsigned*)&sX[r][q * 16];
        const unsigned* w32 = (const unsigned*)(P.wp2 + q * 16);
        float p = 0.f;
#pragma unroll
        for (int k = 0; k < 8; ++k) {
            unsigned a = t32[k], b = w32[k];
            union { unsigned i; float f; } al, ah, bl, bh;
            al.i = a << 16; ah.i = a & 0xffff0000u;
            bl.i = b << 16; bh.i = b & 0xffff0000u;
            p = fmaf(al.f, bl.f, p);
            p = fmaf(ah.f, bh.f, p);
        }
        p += __shfl_xor(p, 1);
        p += __shfl_xor(p, 2);
        p += __shfl_xor(p, 4);
        if (q == 0) {
            float wgt = tanhf(p + bf2f(P.biasp2[0]));
            const size_t pb = (size_t)sDst[r] * 3;
            unsafeAtomicAdd(&pos_acc[pb + 0], wgt * sRel[r][0]);
            unsafeAtomicAdd(&pos_acc[pb + 1], wgt * sRel[r][1]);
            unsafeAtomicAdd(&pos_acc[pb + 2], wgt * sRel[r][2]);
        }
    }
}

// ---------------- update + fused pos output ----------------
__global__ __launch_bounds__(256) void update_kernel(
    const void* __restrict__ rawfeat, const void* __restrict__ rawpos,
    const u16* __restrict__ fU1, const u16* __restrict__ bu1,
    const u16* __restrict__ fU2, const u16* __restrict__ bu2,
    void* __restrict__ outp, const float* __restrict__ magg, const float* __restrict__ pacc,
    const int* __restrict__ flag)
{
    const int tid = threadIdx.x;
    const int lane = tid & 63;
    const int wv = tid >> 6;
    const int row0 = blockIdx.x * 64;
    const int isf = *flag;

    __shared__ u16 sA[64][136];   // features (bf16)
    __shared__ u16 sB[64][136];   // msg_acc -> hidden (reused)

    if (isf) {
        const float* fp = (const float*)rawfeat + (size_t)row0 * HH;
        for (int i = tid; i < 1024; i += 256) {
            int r = i >> 4, c = (i & 15) * 8;
            float4 v0 = *(const float4*)(fp + (size_t)r * HH + c);
            float4 v1 = *(const float4*)(fp + (size_t)r * HH + c + 4);
            uint4 o;
            o.x = (unsigned)f2bf(v0.x) | ((unsigned)f2bf(v0.y) << 16);
            o.y = (unsigned)f2bf(v0.z) | ((unsigned)f2bf(v0.w) << 16);
            o.z = (unsigned)f2bf(v1.x) | ((unsigned)f2bf(v1.y) << 16);
            o.w = (unsigned)f2bf(v1.z) | ((unsigned)f2bf(v1.w) << 16);
            *(uint4*)&sA[r][c] = o;
        }
    } else {
        const uint4* fp = (const uint4*)((const u16*)rawfeat + (size_t)row0 * HH);
        for (int i = tid; i < 1024; i += 256) {
            int r = i >> 4, c = i & 15;
            *(uint4*)&sA[r][c * 8] = fp[i];
        }
    }
    {
        const float4* am = (const float4*)(magg) + (size_t)row0 * 32;
        for (int i = tid; i < 2048; i += 256) {
            int r = i >> 5;
            float4 v = am[i];
            int c = (i & 31) * 4;
            sB[r][c + 0] = f2bf(v.x);
            sB[r][c + 1] = f2bf(v.y);
            sB[r][c + 2] = f2bf(v.z);
            sB[r][c + 3] = f2bf(v.w);
        }
    }
    __syncthreads();

    const int nt0 = wv * 2;
    const int mrow = lane & 15;
    const int kq = (lane >> 4) * 8;
    const int crow = (lane >> 4) * 4;
    const int ccol = lane & 15;

    f32x4 acc[4][2];
#pragma unroll
    for (int mt = 0; mt < 4; ++mt) {
        acc[mt][0] = (f32x4){0.f, 0.f, 0.f, 0.f};
        acc[mt][1] = (f32x4){0.f, 0.f, 0.f, 0.f};
    }
#pragma unroll
    for (int kt = 0; kt < 8; ++kt) {
        const u16* Xb = (kt < 4) ? &sA[0][0] : &sB[0][0];
        const int kk = (kt & 3) * 32 + kq;
        bf16x8 bw0 = *(const bf16x8*)(fU1 + (size_t)(((kt * 8 + nt0) * 64 + lane) * 8));
        bf16x8 bw1 = *(const bf16x8*)(fU1 + (size_t)(((kt * 8 + nt0 + 1) * 64 + lane) * 8));
#pragma unroll
        for (int mt = 0; mt < 4; ++mt) {
            bf16x8 a = *(const bf16x8*)(Xb + (mt * 16 + mrow) * 136 + kk);
            acc[mt][0] = MFMA(a, bw0, acc[mt][0]);
            acc[mt][1] = MFMA(a, bw1, acc[mt][1]);
        }
    }
    __syncthreads();

#pragma unroll
    for (int mt = 0; mt < 4; ++mt) {
#pragma unroll
        for (int n2 = 0; n2 < 2; ++n2) {
            const int col = (nt0 + n2) * 16 + ccol;
            const float bb = bf2f(bu1[col]);
#pragma unroll
            for (int r = 0; r < 4; ++r) {
                const int row = mt * 16 + crow + r;
                sB[row][col] = f2bf(silu_f(acc[mt][n2][r] + bb));
            }
        }
    }
    __syncthreads();

#pragma unroll
    for (int mt = 0; mt < 4; ++mt) {
        acc[mt][0] = (f32x4){0.f, 0.f, 0.f, 0.f};
        acc[mt][1] = (f32x4){0.f, 0.f, 0.f, 0.f};
    }
#pragma unroll
    for (int kt = 0; kt < 4; ++kt) {
        const int kk = kt * 32 + kq;
        bf16x8 bw0 = *(const bf16x8*)(fU2 + (size_t)(((kt * 8 + nt0) * 64 + lane) * 8));
        bf16x8 bw1 = *(const bf16x8*)(fU2 + (size_t)(((kt * 8 + nt0 + 1) * 64 + lane) * 8));
#pragma unroll
        for (int mt = 0; mt < 4; ++mt) {
            bf16x8 a = *(const bf16x8*)(&sB[0][0] + (mt * 16 + mrow) * 136 + kk);
            acc[mt][0] = MFMA(a, bw0, acc[mt][0]);
            acc[mt][1] = MFMA(a, bw1, acc[mt][1]);
        }
    }
#pragma unroll
    for (int mt = 0; mt < 4; ++mt) {
#pragma unroll
        for (int n2 = 0; n2 < 2; ++n2) {
            const int col = (nt0 + n2) * 16 + ccol;
            const float bb = bf2f(bu2[col]);
#pragma unroll
            for (int r = 0; r < 4; ++r) {
                const int row = mt * 16 + crow + r;
                const size_t idx = (size_t)(row0 + row) * HH + col;
                if (isf) {
                    float base = ((const float*)rawfeat)[idx];
                    ((float*)outp)[idx] = acc[mt][n2][r] + bb + base;
                } else {
                    float base = bf2f(sA[row][col]);
                    ((u16*)outp)[idx] = f2bf(acc[mt][n2][r] + bb + base);
                }
            }
        }
    }

    // fused positions output: 3 elems per node row (192 per block)
    if (tid < 192) {
        int i = row0 * 3 + tid;
        float x = pacc[i];
        if (isf) {
            float base = ((const float*)rawpos)[i];
            ((float*)outp)[5120000 + i] = base + 0.5f * x;
        } else {
            float base = bf2f(((const u16*)rawpos)[i]);
            ((u16*)outp)[5120000 + i] = f2bf(base + 0.5f * x);
        }
    }
}

extern "C" void kernel_launch(void* const* d_in, const int* in_sizes, int n_in,
                              void* d_out, int out_size, void* d_ws, size_t ws_size,
                              hipStream_t stream)
{
    // ws layout (bytes):
    //   [0,          20,480,000)  ws_msg f32 (zeroed by prep)
    //   [20,480,000, 20,960,000)  ws_pos f32 (zeroed by prep)
    //   [20,960,000, 21,040,000)  cnt_up  (zeroed by prep)
    //   [21,040,000, 21,120,000)  cnt_dn
    //   [21,120,000, 21,200,000)  cur_up
    //   [21,200,000, 21,280,000)  cur_dn
    //   [21,280,000, 21,280,400)  bsum_up
    //   [21,280,400, 21,280,800)  bsum_dn
    //   [21,280,800, 22,080,800)  es_up
    //   [22,080,800, 22,880,800)  es_dn
    //   [22,880,800, 23,241,248)  weight fragments (180,224 u16)
    //   [23,241,248, 33,804,328)  canonical bf16 feat/pos/deg/small-weights (5,281,540 u16)
    //   [33,804,328, +4)          flag
    float* ws_msg  = (float*)d_ws;
    float* ws_pos  = (float*)((char*)d_ws + 20480000);
    int*   cnt_up  = (int*)((char*)d_ws + 20960000);
    int*   cnt_dn  = (int*)((char*)d_ws + 21040000);
    int*   cur_up  = (int*)((char*)d_ws + 21120000);
    int*   cur_dn  = (int*)((char*)d_ws + 21200000);
    int*   bsum_up = (int*)((char*)d_ws + 21280000);
    int*   bsum_dn = (int*)((char*)d_ws + 21280400);
    int*   es_up   = (int*)((char*)d_ws + 21280800);
    int*   es_dn   = (int*)((char*)d_ws + 22080800);
    u16*   fbase   = (u16*)((char*)d_ws + 22880800);
    u16*   canon   = (u16*)((char*)d_ws + 23241248);
    int*   flag    = (int*)((char*)d_ws + 33804328);
    if (ws_size < 33804332ULL) return;

    u16* f_m1u = fbase;              // 32768 (K=256)
    u16* f_m2u = fbase + 32768;
    u16* f_p1u = fbase + 49152;
    u16* f_m1d = fbase + 65536;
    u16* f_m2d = fbase + 98304;
    u16* f_p1d = fbase + 114688;
    u16* f_u1  = fbase + 131072;
    u16* f_u2  = fbase + 163840;

    u16* cfeat  = canon;
    u16* cpos   = canon + 5120000;
    u16* cdgu   = canon + 5240000;
    u16* cdgd   = canon + 5260000;
    u16* cw1lu  = canon + 5280000;
    u16* cb1u   = canon + 5280128;
    u16* cb2u   = canon + 5280256;
    u16* cbp1u  = canon + 5280384;
    u16* cwp2u  = canon + 5280512;
    u16* cbp2u  = canon + 5280640;
    u16* cw1ld  = canon + 5280642;
    u16* cb1d   = canon + 5280770;
    u16* cb2d   = canon + 5280898;
    u16* cbp1d  = canon + 5281026;
    u16* cwp2d  = canon + 5281154;
    u16* cbp2d  = canon + 5281282;
    u16* cbu1   = canon + 5281284;
    u16* cbu2   = canon + 5281412;

    const int* ei_up = (const int*)d_in[2];
    const int* ei_dn = (const int*)d_in[3];

    detect_kernel<<<1, 256, 0, stream>>>((const u16*)d_in[0], flag);

    prep_kernel<<<(5280000 + 255) / 256, 256, 0, stream>>>(ws_msg, cnt_up);

    P18 cp;
    cp.p[0] = d_in[0];  cp.p[1] = d_in[1];  cp.p[2] = d_in[4];  cp.p[3] = d_in[5];
    cp.p[4] = d_in[6];  cp.p[5] = d_in[7];  cp.p[6] = d_in[9];  cp.p[7] = d_in[11];
    cp.p[8] = d_in[12]; cp.p[9] = d_in[13];
    cp.p[10] = d_in[14]; cp.p[11] = d_in[15]; cp.p[12] = d_in[17]; cp.p[13] = d_in[19];
    cp.p[14] = d_in[20]; cp.p[15] = d_in[21];
    cp.p[16] = d_in[23]; cp.p[17] = d_in[25];
    canon5_kernel<<<(C5TOT + 255) / 256, 256, 0, stream>>>(cp, canon, flag);

    P8 wsf;
    wsf.w[0] = d_in[6];  wsf.w[1] = d_in[8];  wsf.w[2] = d_in[10]; wsf.w[3] = d_in[14];
    wsf.w[4] = d_in[16]; wsf.w[5] = d_in[18]; wsf.w[6] = d_in[22]; wsf.w[7] = d_in[24];
    make_frag_all<<<(FTOT + 255) / 256, 256, 0, stream>>>(wsf, fbase, flag);

    count2_kernel<<<(2 * EE + 255) / 256, 256, 0, stream>>>(ei_up, ei_dn, cnt_up, cnt_dn);
    SP sp;
    sp.cnt[0] = cnt_up; sp.cnt[1] = cnt_dn;
    sp.cur[0] = cur_up; sp.cur[1] = cur_dn;
    sp.bsum[0] = bsum_up; sp.bsum[1] = bsum_dn;
    scan1_kernel<<<2 * NBLK, 256, 0, stream>>>(sp);
    scan2_kernel<<<1, 256, 0, stream>>>(bsum_up, bsum_dn);
    scatter2_kernel<<<(2 * EE + 255) / 256, 256, 0, stream>>>(ei_up, ei_dn, cur_up, bsum_up,
                                                              cur_dn, bsum_dn, es_up, es_dn);

    EP up, dn;
    up.eidx = ei_up; up.es = es_up; up.deg = cdgu;
    up.fW1 = f_m1u; up.fW2 = f_m2u; up.fP1 = f_p1u;
    up.w1last = cw1lu; up.bias1 = cb1u; up.bias2 = cb2u;
    up.biasp1 = cbp1u; up.wp2 = cwp2u; up.biasp2 = cbp2u;
    dn.eidx = ei_dn; dn.es = es_dn; dn.deg = cdgd;
    dn.fW1 = f_m1d; dn.fW2 = f_m2d; dn.fP1 = f_p1d;
    dn.w1last = cw1ld; dn.bias1 = cb1d; dn.bias2 = cb2d;
    dn.biasp1 = cbp1d; dn.wp2 = cwp2d; dn.biasp2 = cbp2d;

    edge_kernel<<<2 * BB * EBLK, 512, 0, stream>>>(cfeat, cpos, up, dn, ws_msg, ws_pos);

    update_kernel<<<625, 256, 0, stream>>>(d_in[0], d_in[1], f_u1, cbu1, f_u2, cbu2,
                                           d_out, ws_msg, ws_pos, flag);
}

// Round 10
// 517.277 us; speedup vs baseline: 1.1292x; 1.0172x over previous
//
#include <hip/hip_runtime.h>

#define BB 2
#define NN 20000
#define HH 128
#define EE 200000
#define EBLK 3125   // EE / 64
#define NBLK 79     // ceil(NN/256)

typedef unsigned short u16;
typedef __attribute__((ext_vector_type(4))) float f32x4;
typedef __bf16 bf16x8 __attribute__((ext_vector_type(8)));

#define MFMA(a, b, c) __builtin_amdgcn_mfma_f32_16x16x32_bf16((a), (b), (c), 0, 0, 0)

__device__ __forceinline__ float bf2f(u16 u) {
    union { unsigned int i; float f; } v; v.i = ((unsigned int)u) << 16; return v.f;
}
__device__ __forceinline__ u16 f2bf(float f) {
    union { __bf16 h; u16 u; } v; v.h = (__bf16)f; return v.u;
}
#if __has_builtin(__builtin_amdgcn_rcpf)
__device__ __forceinline__ float rcpf(float x) { return __builtin_amdgcn_rcpf(x); }
#else
__device__ __forceinline__ float rcpf(float x) { return 1.f / x; }
#endif
__device__ __forceinline__ float silu_f(float z) { return z * rcpf(1.f + __expf(-z)); }
// flag-routed load (setup kernels only): f32 raw or bf16 raw
__device__ __forceinline__ float ldv(const void* p, long i, int f) {
    return f ? ((const float*)p)[i] : bf2f(((const u16*)p)[i]);
}

// ---------------- launch 1: dtype detection + cnt zeroing ----------------
__global__ __launch_bounds__(256) void detect_zero_kernel(const u16* __restrict__ f,
                                                          int* __restrict__ flag,
                                                          int* __restrict__ cnt) {
    int i = blockIdx.x * 256 + threadIdx.x;
    if (i < 40000) cnt[i] = 0;            // cnt_up | cnt_dn contiguous
    if (blockIdx.x == 0) {
        int tid = threadIdx.x;
        u16 v = f[tid * 2];
        int e = (v >> 7) & 0xFF;
        int ok = (e >= 101 && e <= 143) ? 1 : 0;
        __shared__ int c;
        if (tid == 0) c = 0;
        __syncthreads();
        atomicAdd(&c, ok);
        __syncthreads();
        if (tid == 0) *flag = (c < 200) ? 1 : 0;   // 1 => inputs are float32
    }
}

// ---------------- launch 2: fused setup ----------------
// ranges: [0,R0) zero ws accumulators | [R0,R1) canon | [R1,R2) weight frags
//         [R2,R3) edge-count atomics (cnt zeroed in launch 1)
#define C5TOT 5281540
#define FTOT 180224
#define R0 5240000
#define R1 (R0 + C5TOT)
#define R2 (R1 + FTOT)
#define R3 (R2 + 2 * EE)
struct P18 { const void* p[18]; };
struct P8 { const void* w[8]; };

__global__ __launch_bounds__(256) void setup_kernel(
    P18 cp, P8 wf, const int* __restrict__ eu, const int* __restrict__ ed,
    float* __restrict__ ws_acc, u16* __restrict__ canon, u16* __restrict__ fbase,
    int* __restrict__ cnt_up, int* __restrict__ cnt_dn, const int* __restrict__ flag)
{
    long i = (long)blockIdx.x * 256 + threadIdx.x;
    if (i < R0) { ws_acc[i] = 0.f; return; }
    if (i < R1) {
        // canonicalize feat/pos/deg + small weights to bf16
        static const int off[19] = {
            0, 5120000, 5240000, 5260000, 5280000,
            5280128, 5280256, 5280384, 5280512, 5280640,
            5280642, 5280770, 5280898, 5281026, 5281154, 5281282,
            5281284, 5281412, 5281540 };
        static const int rsz[18] = {
            5120000, 120000, 20000, 20000,
            128, 128, 128, 128, 128, 1,
            128, 128, 128, 128, 128, 1,
            128, 128 };
        static const int soff[18] = {
            0, 0, 0, 0,
            32768, 0, 0, 0, 0, 0,
            32768, 0, 0, 0, 0, 0,
            0, 0 };
        int j = (int)(i - R0);
        int isf = *flag;
        int t = 0;
#pragma unroll 1
        while (j >= off[t + 1]) ++t;
        int k = j - off[t];
        u16 v = 0;
        if (k < rsz[t]) v = f2bf(ldv(cp.p[t], (long)soff[t] + k, isf));
        canon[j] = v;
        return;
    }
    if (i < R2) {
        // weight fragment permutation
        static const int foff[9] = { 0, 32768, 49152, 65536, 98304, 114688,
                                     131072, 163840, 180224 };
        int j = (int)(i - R1);
        int isf = *flag;
        int t = 0;
#pragma unroll 1
        while (j >= foff[t + 1]) ++t;
        int m = j - foff[t];
        int jj = m & 7, lane = (m >> 3) & 63, nt = (m >> 9) & 7, kt = m >> 12;
        int k = kt * 32 + ((lane >> 4) * 8) + jj;
        int n = nt * 16 + (lane & 15);
        fbase[j] = f2bf(ldv(wf.w[t], (long)k * 128 + n, isf));
        return;
    }
    if (i < R3) {
        int e = (int)(i - R2);
        if (e < EE) atomicAdd(&cnt_up[eu[EE + e]], 1);
        else atomicAdd(&cnt_dn[ed[EE + e - EE]], 1);
    }
}

// ---------------- CSR scans + scatter ----------------
struct SP { const int* cnt[2]; int* cur[2]; int* bsum[2]; };

__global__ __launch_bounds__(256) void scan1_kernel(SP p) {
    int half = blockIdx.x / NBLK;
    int b = blockIdx.x - half * NBLK;
    int t = threadIdx.x;
    int i = b * 256 + t;
    __shared__ int buf[256];
    int v = (i < NN) ? p.cnt[half][i] : 0;
    buf[t] = v;
    __syncthreads();
    for (int s = 1; s < 256; s <<= 1) {
        int x = (t >= s) ? buf[t - s] : 0;
        __syncthreads();
        buf[t] += x;
        __syncthreads();
    }
    if (i < NN) p.cur[half][i] = buf[t] - v;   // exclusive within block
    if (t == 255) p.bsum[half][b] = buf[255];
}

__global__ __launch_bounds__(256) void scan2_kernel(int* __restrict__ bu, int* __restrict__ bd) {
    __shared__ int buf[2][128];
    int half = threadIdx.x >> 7, t = threadIdx.x & 127;
    int* bs = half ? bd : bu;
    int v = (t < NBLK) ? bs[t] : 0;
    buf[half][t] = v;
    __syncthreads();
    for (int s = 1; s < 128; s <<= 1) {
        int x = (t >= s) ? buf[half][t - s] : 0;
        __syncthreads();
        buf[half][t] += x;
        __syncthreads();
    }
    if (t < NBLK) bs[t] = buf[half][t] - v;    // exclusive block offsets
}

__global__ void scatter2_kernel(const int* __restrict__ eu, const int* __restrict__ ed,
                                int* __restrict__ cu, const int* __restrict__ bu,
                                int* __restrict__ cd, const int* __restrict__ bd,
                                int* __restrict__ su, int* __restrict__ sd) {
    int e = blockIdx.x * 256 + threadIdx.x;
    if (e < EE) {
        int d = eu[EE + e];
        int p = atomicAdd(&cu[d], 1) + bu[d >> 8];
        su[p] = e;
    } else {
        e -= EE;
        if (e < EE) {
            int d = ed[EE + e];
            int p = atomicAdd(&cd[d], 1) + bd[d >> 8];
            sd[p] = e;
        }
    }
}

// ---------------- edge kernel (r9 structure, unchanged) ----------------
struct EP {
    const int* eidx; const int* es; const u16* deg;
    const u16* fW1; const u16* fW2; const u16* fP1;
    const u16* w1last; const u16* bias1; const u16* bias2;
    const u16* biasp1; const u16* wp2; const u16* biasp2;
};

__global__ __launch_bounds__(512, 8) void edge_kernel(
    const u16* __restrict__ feat, const u16* __restrict__ posit,   // canonical bf16
    EP up, EP dn,
    float* __restrict__ msg_base, float* __restrict__ pos_base)
{
    const int tid = threadIdx.x;
    const int lane = tid & 63;
    const int wv = tid >> 6;              // 0..7 = n-tile
    const int half = blockIdx.x / (BB * EBLK);
    const int rem = blockIdx.x - half * (BB * EBLK);
    const int bb = rem / EBLK;
    const int s0 = (rem - bb * EBLK) * 64;
    const EP P = half ? dn : up;
    float* msg_acc = msg_base + (size_t)bb * NN * HH;
    float* pos_acc = pos_base + (size_t)bb * NN * 3;

    __shared__ u16 sX[64][136];   // h_src -> msg-hidden -> pos-hidden
    __shared__ u16 sY[64][136];   // h_dst -> messages
    __shared__ float sRel[64][3];
    __shared__ float sDist[64];
    __shared__ float sInv[64];
    __shared__ int sDst[64];

    // meta (no barrier needed before gather: consumed only after B2/B4/B5)
    if (tid < 64) {
        int e = P.es[s0 + tid];
        int s = P.eidx[e];
        int d = P.eidx[EE + e];
        sDst[tid] = d;
        sInv[tid] = 1.f / fmaxf(bf2f(P.deg[d]), 1.f);
        const u16* ps = posit + ((size_t)bb * NN + s) * 3;
        const u16* pd = posit + ((size_t)bb * NN + d) * 3;
        float dx = bf2f(ps[0]) - bf2f(pd[0]);
        float dy = bf2f(ps[1]) - bf2f(pd[1]);
        float dz = bf2f(ps[2]) - bf2f(pd[2]);
        sRel[tid][0] = dx; sRel[tid][1] = dy; sRel[tid][2] = dz;
        sDist[tid] = sqrtf(dx * dx + dy * dy + dz * dz);
    }

    // gather h_src -> sX, h_dst -> sY; each thread fetches its own indices
    {
        const int r = tid >> 3, part = tid & 7;
        int e = P.es[s0 + r];
        int s = P.eidx[e];
        int d = P.eidx[EE + e];
        const uint4* fs = (const uint4*)(feat + ((size_t)bb * NN + s) * HH);
        const uint4* fd = (const uint4*)(feat + ((size_t)bb * NN + d) * HH);
        uint4* as = (uint4*)&sX[r][part * 16];
        uint4* ad = (uint4*)&sY[r][part * 16];
#pragma unroll
        for (int i = 0; i < 2; ++i) { as[i] = fs[part * 2 + i]; ad[i] = fd[part * 2 + i]; }
    }
    __syncthreads();   // B1

    const int nt = wv;
    const int mrow = lane & 15;
    const int kq = (lane >> 4) * 8;
    const int crow = (lane >> 4) * 4;
    const int ccol = lane & 15;
    const int col = nt * 16 + ccol;

    f32x4 acc[4];
#pragma unroll
    for (int mt = 0; mt < 4; ++mt) acc[mt] = (f32x4){0.f, 0.f, 0.f, 0.f};

    // ----- msg layer 1 : [h_src | h_dst] @ W1[0:256]  (K=256) -----
#pragma unroll
    for (int kt = 0; kt < 8; ++kt) {
        const u16* Xb = (kt < 4) ? &sX[0][0] : &sY[0][0];
        const int kk = (kt & 3) * 32 + kq;
        bf16x8 bw = *(const bf16x8*)(P.fW1 + (size_t)(((kt * 8 + nt) * 64 + lane) * 8));
#pragma unroll
        for (int mt = 0; mt < 4; ++mt) {
            bf16x8 a = *(const bf16x8*)(Xb + (mt * 16 + mrow) * 136 + kk);
            acc[mt] = MFMA(a, bw, acc[mt]);
        }
    }
    __syncthreads();   // B2: all L1 reads of sX/sY done

    // epilogue: + dist*W1[256] + b1, silu -> sX
    {
        const float wl = bf2f(P.w1last[col]);
        const float bb2 = bf2f(P.bias1[col]);
#pragma unroll
        for (int mt = 0; mt < 4; ++mt) {
#pragma unroll
            for (int r = 0; r < 4; ++r) {
                const int row = mt * 16 + crow + r;
                float z = fmaf(sDist[row], wl, acc[mt][r]) + bb2;
                sX[row][col] = f2bf(silu_f(z));
            }
        }
    }
    __syncthreads();   // B3

    // ----- msg layer 2 : sX @ W2 + b2 = messages -> sY (K=128) -----
#pragma unroll
    for (int mt = 0; mt < 4; ++mt) acc[mt] = (f32x4){0.f, 0.f, 0.f, 0.f};
#pragma unroll
    for (int kt = 0; kt < 4; ++kt) {
        const int kk = kt * 32 + kq;
        bf16x8 bw = *(const bf16x8*)(P.fW2 + (size_t)(((kt * 8 + nt) * 64 + lane) * 8));
#pragma unroll
        for (int mt = 0; mt < 4; ++mt) {
            bf16x8 a = *(const bf16x8*)(&sX[0][0] + (mt * 16 + mrow) * 136 + kk);
            acc[mt] = MFMA(a, bw, acc[mt]);
        }
    }
    {
        const float bb2 = bf2f(P.bias2[col]);
#pragma unroll
        for (int mt = 0; mt < 4; ++mt) {
#pragma unroll
            for (int r = 0; r < 4; ++r) {
                const int row = mt * 16 + crow + r;
                sY[row][col] = f2bf(acc[mt][r] + bb2);
            }
        }
    }
    __syncthreads();   // B4: messages visible; all reads of sX done

    // ----- pos layer 1 : silu(messages @ P1 + bp1) -> sX (K=128) -----
#pragma unroll
    for (int mt = 0; mt < 4; ++mt) acc[mt] = (f32x4){0.f, 0.f, 0.f, 0.f};
#pragma unroll
    for (int kt = 0; kt < 4; ++kt) {
        const int kk = kt * 32 + kq;
        bf16x8 bw = *(const bf16x8*)(P.fP1 + (size_t)(((kt * 8 + nt) * 64 + lane) * 8));
#pragma unroll
        for (int mt = 0; mt < 4; ++mt) {
            bf16x8 a = *(const bf16x8*)(&sY[0][0] + (mt * 16 + mrow) * 136 + kk);
            acc[mt] = MFMA(a, bw, acc[mt]);
        }
    }

    // segment-reduced scatter of messages (rows sorted by dst):
    // 512 threads = 128 cols x 4 row-spans of 16, pre-scaled by 1/clip(deg)
    {
        const int scol = tid & 127;
        const int r0 = (tid >> 7) * 16;
        float accv = 0.f;
        int dprev = sDst[r0];
        float invprev = sInv[r0];
#pragma unroll 1
        for (int r = r0; r < r0 + 16; ++r) {
            int dcur = sDst[r];
            if (dcur != dprev) {
                unsafeAtomicAdd(&msg_acc[(size_t)dprev * HH + scol], accv * invprev);
                accv = 0.f; dprev = dcur; invprev = sInv[r];
            }
            accv += bf2f(sY[r][scol]);
        }
        unsafeAtomicAdd(&msg_acc[(size_t)dprev * HH + scol], accv * invprev);
    }

    // pos1 epilogue -> sX
    {
        const float bb2 = bf2f(P.biasp1[col]);
#pragma unroll
        for (int mt = 0; mt < 4; ++mt) {
#pragma unroll
            for (int r = 0; r < 4; ++r) {
                const int row = mt * 16 + crow + r;
                sX[row][col] = f2bf(silu_f(acc[mt][r] + bb2));
            }
        }
    }
    __syncthreads();   // B5

    // ----- pos layer 2 : tanh(hidden @ p2 + bp2) ; scatter wgt*rel_pos -----
    {
        const int r = tid >> 3, q = tid & 7;
        const unsigned* t32 = (const unsigned*)&sX[r][q * 16];
        const unsigned* w32 = (const unsigned*)(P.wp2 + q * 16);
        float p = 0.f;
#pragma unroll
        for (int k = 0; k < 8; ++k) {
            unsigned a = t32[k], b = w32[k];
            union { unsigned i; float f; } al, ah, bl, bh;
            al.i = a << 16; ah.i = a & 0xffff0000u;
            bl.i = b << 16; bh.i = b & 0xffff0000u;
            p = fmaf(al.f, bl.f, p);
            p = fmaf(ah.f, bh.f, p);
        }
        p += __shfl_xor(p, 1);
        p += __shfl_xor(p, 2);
        p += __shfl_xor(p, 4);
        if (q == 0) {
            float wgt = tanhf(p + bf2f(P.biasp2[0]));
            const size_t pb = (size_t)sDst[r] * 3;
            unsafeAtomicAdd(&pos_acc[pb + 0], wgt * sRel[r][0]);
            unsafeAtomicAdd(&pos_acc[pb + 1], wgt * sRel[r][1]);
            unsafeAtomicAdd(&pos_acc[pb + 2], wgt * sRel[r][2]);
        }
    }
}

// ---------------- update + fused pos output ----------------
__global__ __launch_bounds__(256) void update_kernel(
    const void* __restrict__ rawfeat, const void* __restrict__ rawpos,
    const u16* __restrict__ fU1, const u16* __restrict__ bu1,
    const u16* __restrict__ fU2, const u16* __restrict__ bu2,
    void* __restrict__ outp, const float* __restrict__ magg, const float* __restrict__ pacc,
    const int* __restrict__ flag)
{
    const int tid = threadIdx.x;
    const int lane = tid & 63;
    const int wv = tid >> 6;
    const int row0 = blockIdx.x * 64;
    const int isf = *flag;

    __shared__ u16 sA[64][136];   // features (bf16)
    __shared__ u16 sB[64][136];   // msg_acc -> hidden (reused)

    if (isf) {
        const float* fp = (const float*)rawfeat + (size_t)row0 * HH;
        for (int i = tid; i < 1024; i += 256) {
            int r = i >> 4, c = (i & 15) * 8;
            float4 v0 = *(const float4*)(fp + (size_t)r * HH + c);
            float4 v1 = *(const float4*)(fp + (size_t)r * HH + c + 4);
            uint4 o;
            o.x = (unsigned)f2bf(v0.x) | ((unsigned)f2bf(v0.y) << 16);
            o.y = (unsigned)f2bf(v0.z) | ((unsigned)f2bf(v0.w) << 16);
            o.z = (unsigned)f2bf(v1.x) | ((unsigned)f2bf(v1.y) << 16);
            o.w = (unsigned)f2bf(v1.z) | ((unsigned)f2bf(v1.w) << 16);
            *(uint4*)&sA[r][c] = o;
        }
    } else {
        const uint4* fp = (const uint4*)((const u16*)rawfeat + (size_t)row0 * HH);
        for (int i = tid; i < 1024; i += 256) {
            int r = i >> 4, c = i & 15;
            *(uint4*)&sA[r][c * 8] = fp[i];
        }
    }
    {
        const float4* am = (const float4*)(magg) + (size_t)row0 * 32;
        for (int i = tid; i < 2048; i += 256) {
            int r = i >> 5;
            float4 v = am[i];
            int c = (i & 31) * 4;
            sB[r][c + 0] = f2bf(v.x);
            sB[r][c + 1] = f2bf(v.y);
            sB[r][c + 2] = f2bf(v.z);
            sB[r][c + 3] = f2bf(v.w);
        }
    }
    __syncthreads();

    const int nt0 = wv * 2;
    const int mrow = lane & 15;
    const int kq = (lane >> 4) * 8;
    const int crow = (lane >> 4) * 4;
    const int ccol = lane & 15;

    f32x4 acc[4][2];
#pragma unroll
    for (int mt = 0; mt < 4; ++mt) {
        acc[mt][0] = (f32x4){0.f, 0.f, 0.f, 0.f};
        acc[mt][1] = (f32x4){0.f, 0.f, 0.f, 0.f};
    }
#pragma unroll
    for (int kt = 0; kt < 8; ++kt) {
        const u16* Xb = (kt < 4) ? &sA[0][0] : &sB[0][0];
        const int kk = (kt & 3) * 32 + kq;
        bf16x8 bw0 = *(const bf16x8*)(fU1 + (size_t)(((kt * 8 + nt0) * 64 + lane) * 8));
        bf16x8 bw1 = *(const bf16x8*)(fU1 + (size_t)(((kt * 8 + nt0 + 1) * 64 + lane) * 8));
#pragma unroll
        for (int mt = 0; mt < 4; ++mt) {
            bf16x8 a = *(const bf16x8*)(Xb + (mt * 16 + mrow) * 136 + kk);
            acc[mt][0] = MFMA(a, bw0, acc[mt][0]);
            acc[mt][1] = MFMA(a, bw1, acc[mt][1]);
        }
    }
    __syncthreads();

#pragma unroll
    for (int mt = 0; mt < 4; ++mt) {
#pragma unroll
        for (int n2 = 0; n2 < 2; ++n2) {
            const int col = (nt0 + n2) * 16 + ccol;
            const float bb = bf2f(bu1[col]);
#pragma unroll
            for (int r = 0; r < 4; ++r) {
                const int row = mt * 16 + crow + r;
                sB[row][col] = f2bf(silu_f(acc[mt][n2][r] + bb));
            }
        }
    }
    __syncthreads();

#pragma unroll
    for (int mt = 0; mt < 4; ++mt) {
        acc[mt][0] = (f32x4){0.f, 0.f, 0.f, 0.f};
        acc[mt][1] = (f32x4){0.f, 0.f, 0.f, 0.f};
    }
#pragma unroll
    for (int kt = 0; kt < 4; ++kt) {
        const int kk = kt * 32 + kq;
        bf16x8 bw0 = *(const bf16x8*)(fU2 + (size_t)(((kt * 8 + nt0) * 64 + lane) * 8));
        bf16x8 bw1 = *(const bf16x8*)(fU2 + (size_t)(((kt * 8 + nt0 + 1) * 64 + lane) * 8));
#pragma unroll
        for (int mt = 0; mt < 4; ++mt) {
            bf16x8 a = *(const bf16x8*)(&sB[0][0] + (mt * 16 + mrow) * 136 + kk);
            acc[mt][0] = MFMA(a, bw0, acc[mt][0]);
            acc[mt][1] = MFMA(a, bw1, acc[mt][1]);
        }
    }
#pragma unroll
    for (int mt = 0; mt < 4; ++mt) {
#pragma unroll
        for (int n2 = 0; n2 < 2; ++n2) {
            const int col = (nt0 + n2) * 16 + ccol;
            const float bb = bf2f(bu2[col]);
#pragma unroll
            for (int r = 0; r < 4; ++r) {
                const int row = mt * 16 + crow + r;
                const size_t idx = (size_t)(row0 + row) * HH + col;
                if (isf) {
                    float base = ((const float*)rawfeat)[idx];
                    ((float*)outp)[idx] = acc[mt][n2][r] + bb + base;
                } else {
                    float base = bf2f(sA[row][col]);
                    ((u16*)outp)[idx] = f2bf(acc[mt][n2][r] + bb + base);
                }
            }
        }
    }

    // fused positions output: 3 elems per node row (192 per block)
    if (tid < 192) {
        int i = row0 * 3 + tid;
        float x = pacc[i];
        if (isf) {
            float base = ((const float*)rawpos)[i];
            ((float*)outp)[5120000 + i] = base + 0.5f * x;
        } else {
            float base = bf2f(((const u16*)rawpos)[i]);
            ((u16*)outp)[5120000 + i] = f2bf(base + 0.5f * x);
        }
    }
}

extern "C" void kernel_launch(void* const* d_in, const int* in_sizes, int n_in,
                              void* d_out, int out_size, void* d_ws, size_t ws_size,
                              hipStream_t stream)
{
    // ws layout (bytes): identical to round 9
    float* ws_msg  = (float*)d_ws;
    float* ws_pos  = (float*)((char*)d_ws + 20480000);
    int*   cnt_up  = (int*)((char*)d_ws + 20960000);
    int*   cnt_dn  = (int*)((char*)d_ws + 21040000);
    int*   cur_up  = (int*)((char*)d_ws + 21120000);
    int*   cur_dn  = (int*)((char*)d_ws + 21200000);
    int*   bsum_up = (int*)((char*)d_ws + 21280000);
    int*   bsum_dn = (int*)((char*)d_ws + 21280400);
    int*   es_up   = (int*)((char*)d_ws + 21280800);
    int*   es_dn   = (int*)((char*)d_ws + 22080800);
    u16*   fbase   = (u16*)((char*)d_ws + 22880800);
    u16*   canon   = (u16*)((char*)d_ws + 23241248);
    int*   flag    = (int*)((char*)d_ws + 33804328);
    if (ws_size < 33804332ULL) return;

    u16* f_m1u = fbase;              // 32768 (K=256)
    u16* f_m2u = fbase + 32768;
    u16* f_p1u = fbase + 49152;
    u16* f_m1d = fbase + 65536;
    u16* f_m2d = fbase + 98304;
    u16* f_p1d = fbase + 114688;
    u16* f_u1  = fbase + 131072;
    u16* f_u2  = fbase + 163840;

    u16* cfeat  = canon;
    u16* cpos   = canon + 5120000;
    u16* cdgu   = canon + 5240000;
    u16* cdgd   = canon + 5260000;
    u16* cw1lu  = canon + 5280000;
    u16* cb1u   = canon + 5280128;
    u16* cb2u   = canon + 5280256;
    u16* cbp1u  = canon + 5280384;
    u16* cwp2u  = canon + 5280512;
    u16* cbp2u  = canon + 5280640;
    u16* cw1ld  = canon + 5280642;
    u16* cb1d   = canon + 5280770;
    u16* cb2d   = canon + 5280898;
    u16* cbp1d  = canon + 5281026;
    u16* cwp2d  = canon + 5281154;
    u16* cbp2d  = canon + 5281282;
    u16* cbu1   = canon + 5281284;
    u16* cbu2   = canon + 5281412;

    const int* ei_up = (const int*)d_in[2];
    const int* ei_dn = (const int*)d_in[3];

    // launch 1: detect dtype + zero CSR counters
    detect_zero_kernel<<<157, 256, 0, stream>>>((const u16*)d_in[0], flag, cnt_up);

    // launch 2: fused setup (ws zero | canon | frags | edge counts)
    P18 cp;
    cp.p[0] = d_in[0];  cp.p[1] = d_in[1];  cp.p[2] = d_in[4];  cp.p[3] = d_in[5];
    cp.p[4] = d_in[6];  cp.p[5] = d_in[7];  cp.p[6] = d_in[9];  cp.p[7] = d_in[11];
    cp.p[8] = d_in[12]; cp.p[9] = d_in[13];
    cp.p[10] = d_in[14]; cp.p[11] = d_in[15]; cp.p[12] = d_in[17]; cp.p[13] = d_in[19];
    cp.p[14] = d_in[20]; cp.p[15] = d_in[21];
    cp.p[16] = d_in[23]; cp.p[17] = d_in[25];
    P8 wsf;
    wsf.w[0] = d_in[6];  wsf.w[1] = d_in[8];  wsf.w[2] = d_in[10]; wsf.w[3] = d_in[14];
    wsf.w[4] = d_in[16]; wsf.w[5] = d_in[18]; wsf.w[6] = d_in[22]; wsf.w[7] = d_in[24];
    setup_kernel<<<(R3 + 255) / 256, 256, 0, stream>>>(cp, wsf, ei_up, ei_dn,
                                                       ws_msg, canon, fbase,
                                                       cnt_up, cnt_dn, flag);

    // launches 3-5: CSR scan + scatter
    SP sp;
    sp.cnt[0] = cnt_up; sp.cnt[1] = cnt_dn;
    sp.cur[0] = cur_up; sp.cur[1] = cur_dn;
    sp.bsum[0] = bsum_up; sp.bsum[1] = bsum_dn;
    scan1_kernel<<<2 * NBLK, 256, 0, stream>>>(sp);
    scan2_kernel<<<1, 256, 0, stream>>>(bsum_up, bsum_dn);
    scatter2_kernel<<<(2 * EE + 255) / 256, 256, 0, stream>>>(ei_up, ei_dn, cur_up, bsum_up,
                                                              cur_dn, bsum_dn, es_up, es_dn);

    // launch 6: edge kernel
    EP up, dn;
    up.eidx = ei_up; up.es = es_up; up.deg = cdgu;
    up.fW1 = f_m1u; up.fW2 = f_m2u; up.fP1 = f_p1u;
    up.w1last = cw1lu; up.bias1 = cb1u; up.bias2 = cb2u;
    up.biasp1 = cbp1u; up.wp2 = cwp2u; up.biasp2 = cbp2u;
    dn.eidx = ei_dn; dn.es = es_dn; dn.deg = cdgd;
    dn.fW1 = f_m1d; dn.fW2 = f_m2d; dn.fP1 = f_p1d;
    dn.w1last = cw1ld; dn.bias1 = cb1d; dn.bias2 = cb2d;
    dn.biasp1 = cbp1d; dn.wp2 = cwp2d; dn.biasp2 = cbp2d;
    edge_kernel<<<2 * BB * EBLK, 512, 0, stream>>>(cfeat, cpos, up, dn, ws_msg, ws_pos);

    // launch 7: update + positions out
    update_kernel<<<625, 256, 0, stream>>>(d_in[0], d_in[1], f_u1, cbu1, f_u2, cbu2,
                                           d_out, ws_msg, ws_pos, flag);
}

// Round 11
// 508.348 us; speedup vs baseline: 1.1490x; 1.0176x over previous
//
#include <hip/hip_runtime.h>

#define BB 2
#define NN 20000
#define HH 128
#define EE 200000
#define TR 128      // edge rows per block
#define NEB 1563    // ceil(EE/128)
#define NBLK 79     // ceil(NN/256)

typedef unsigned short u16;
typedef __attribute__((ext_vector_type(4))) float f32x4;
typedef __bf16 bf16x8 __attribute__((ext_vector_type(8)));

#define MFMA(a, b, c) __builtin_amdgcn_mfma_f32_16x16x32_bf16((a), (b), (c), 0, 0, 0)

__device__ __forceinline__ float bf2f(u16 u) {
    union { unsigned int i; float f; } v; v.i = ((unsigned int)u) << 16; return v.f;
}
__device__ __forceinline__ u16 f2bf(float f) {
    union { __bf16 h; u16 u; } v; v.h = (__bf16)f; return v.u;
}
#if __has_builtin(__builtin_amdgcn_rcpf)
__device__ __forceinline__ float rcpf(float x) { return __builtin_amdgcn_rcpf(x); }
#else
__device__ __forceinline__ float rcpf(float x) { return 1.f / x; }
#endif
__device__ __forceinline__ float silu_f(float z) { return z * rcpf(1.f + __expf(-z)); }
// flag-routed load (setup kernels only): f32 raw or bf16 raw
__device__ __forceinline__ float ldv(const void* p, long i, int f) {
    return f ? ((const float*)p)[i] : bf2f(((const u16*)p)[i]);
}

// ---------------- launch 1: dtype detection + cnt zeroing ----------------
__global__ __launch_bounds__(256) void detect_zero_kernel(const u16* __restrict__ f,
                                                          int* __restrict__ flag,
                                                          int* __restrict__ cnt) {
    int i = blockIdx.x * 256 + threadIdx.x;
    if (i < 40000) cnt[i] = 0;            // cnt_up | cnt_dn contiguous
    if (blockIdx.x == 0) {
        int tid = threadIdx.x;
        u16 v = f[tid * 2];
        int e = (v >> 7) & 0xFF;
        int ok = (e >= 101 && e <= 143) ? 1 : 0;
        __shared__ int c;
        if (tid == 0) c = 0;
        __syncthreads();
        atomicAdd(&c, ok);
        __syncthreads();
        if (tid == 0) *flag = (c < 200) ? 1 : 0;   // 1 => inputs are float32
    }
}

// ---------------- launch 2: fused setup ----------------
#define C5TOT 5281540
#define FTOT 180224
#define R0 5240000
#define R1 (R0 + C5TOT)
#define R2 (R1 + FTOT)
#define R3 (R2 + 2 * EE)
struct P18 { const void* p[18]; };
struct P8 { const void* w[8]; };

__global__ __launch_bounds__(256) void setup_kernel(
    P18 cp, P8 wf, const int* __restrict__ eu, const int* __restrict__ ed,
    float* __restrict__ ws_acc, u16* __restrict__ canon, u16* __restrict__ fbase,
    int* __restrict__ cnt_up, int* __restrict__ cnt_dn, const int* __restrict__ flag)
{
    long i = (long)blockIdx.x * 256 + threadIdx.x;
    if (i < R0) { ws_acc[i] = 0.f; return; }
    if (i < R1) {
        static const int off[19] = {
            0, 5120000, 5240000, 5260000, 5280000,
            5280128, 5280256, 5280384, 5280512, 5280640,
            5280642, 5280770, 5280898, 5281026, 5281154, 5281282,
            5281284, 5281412, 5281540 };
        static const int rsz[18] = {
            5120000, 120000, 20000, 20000,
            128, 128, 128, 128, 128, 1,
            128, 128, 128, 128, 128, 1,
            128, 128 };
        static const int soff[18] = {
            0, 0, 0, 0,
            32768, 0, 0, 0, 0, 0,
            32768, 0, 0, 0, 0, 0,
            0, 0 };
        int j = (int)(i - R0);
        int isf = *flag;
        int t = 0;
#pragma unroll 1
        while (j >= off[t + 1]) ++t;
        int k = j - off[t];
        u16 v = 0;
        if (k < rsz[t]) v = f2bf(ldv(cp.p[t], (long)soff[t] + k, isf));
        canon[j] = v;
        return;
    }
    if (i < R2) {
        static const int foff[9] = { 0, 32768, 49152, 65536, 98304, 114688,
                                     131072, 163840, 180224 };
        int j = (int)(i - R1);
        int isf = *flag;
        int t = 0;
#pragma unroll 1
        while (j >= foff[t + 1]) ++t;
        int m = j - foff[t];
        int jj = m & 7, lane = (m >> 3) & 63, nt = (m >> 9) & 7, kt = m >> 12;
        int k = kt * 32 + ((lane >> 4) * 8) + jj;
        int n = nt * 16 + (lane & 15);
        fbase[j] = f2bf(ldv(wf.w[t], (long)k * 128 + n, isf));
        return;
    }
    if (i < R3) {
        int e = (int)(i - R2);
        if (e < EE) atomicAdd(&cnt_up[eu[EE + e]], 1);
        else atomicAdd(&cnt_dn[ed[EE + e - EE]], 1);
    }
}

// ---------------- CSR scans + scatter ----------------
struct SP { const int* cnt[2]; int* cur[2]; int* bsum[2]; };

__global__ __launch_bounds__(256) void scan1_kernel(SP p) {
    int half = blockIdx.x / NBLK;
    int b = blockIdx.x - half * NBLK;
    int t = threadIdx.x;
    int i = b * 256 + t;
    __shared__ int buf[256];
    int v = (i < NN) ? p.cnt[half][i] : 0;
    buf[t] = v;
    __syncthreads();
    for (int s = 1; s < 256; s <<= 1) {
        int x = (t >= s) ? buf[t - s] : 0;
        __syncthreads();
        buf[t] += x;
        __syncthreads();
    }
    if (i < NN) p.cur[half][i] = buf[t] - v;   // exclusive within block
    if (t == 255) p.bsum[half][b] = buf[255];
}

__global__ __launch_bounds__(256) void scan2_kernel(int* __restrict__ bu, int* __restrict__ bd) {
    __shared__ int buf[2][128];
    int half = threadIdx.x >> 7, t = threadIdx.x & 127;
    int* bs = half ? bd : bu;
    int v = (t < NBLK) ? bs[t] : 0;
    buf[half][t] = v;
    __syncthreads();
    for (int s = 1; s < 128; s <<= 1) {
        int x = (t >= s) ? buf[half][t - s] : 0;
        __syncthreads();
        buf[half][t] += x;
        __syncthreads();
    }
    if (t < NBLK) bs[t] = buf[half][t] - v;    // exclusive block offsets
}

__global__ void scatter2_kernel(const int* __restrict__ eu, const int* __restrict__ ed,
                                int* __restrict__ cu, const int* __restrict__ bu,
                                int* __restrict__ cd, const int* __restrict__ bd,
                                int* __restrict__ su, int* __restrict__ sd) {
    int e = blockIdx.x * 256 + threadIdx.x;
    if (e < EE) {
        int d = eu[EE + e];
        int p = atomicAdd(&cu[d], 1) + bu[d >> 8];
        su[p] = e;
    } else {
        e -= EE;
        if (e < EE) {
            int d = ed[EE + e];
            int p = atomicAdd(&cd[d], 1) + bd[d >> 8];
            sd[p] = e;
        }
    }
}

// ---------------- edge kernel: 128 edge-rows per block ----------------
struct EP {
    const int* eidx; const int* es; const u16* deg;
    const u16* fW1; const u16* fW2; const u16* fP1;
    const u16* w1last; const u16* bias1; const u16* bias2;
    const u16* biasp1; const u16* wp2; const u16* biasp2;
};

__global__ __launch_bounds__(512, 4) void edge_kernel(
    const u16* __restrict__ feat, const u16* __restrict__ posit,   // canonical bf16
    EP up, EP dn,
    float* __restrict__ msg_base, float* __restrict__ pos_base)
{
    const int tid = threadIdx.x;
    const int lane = tid & 63;
    const int wv = tid >> 6;              // 0..7 = n-tile
    const int half = blockIdx.x / (BB * NEB);
    const int rem = blockIdx.x - half * (BB * NEB);
    const int bb = rem / NEB;
    const int s0 = (rem - bb * NEB) * TR;
    const EP P = half ? dn : up;
    float* msg_acc = msg_base + (size_t)bb * NN * HH;
    float* pos_acc = pos_base + (size_t)bb * NN * 3;

    __shared__ u16 sX[TR][136];   // h_src -> msg-hidden -> pos-hidden
    __shared__ u16 sY[TR][136];   // h_dst -> messages
    __shared__ float sRel[TR][3];
    __shared__ float sDist[TR];
    __shared__ float sInv[TR];
    __shared__ int sDst[TR];

    // meta (no barrier needed before gather: consumed only after B2/B4/B5)
    if (tid < TR) {
        int slot = s0 + tid; if (slot >= EE) slot = EE - 1;   // replicate last edge
        int e = P.es[slot];
        int s = P.eidx[e];
        int d = P.eidx[EE + e];
        sDst[tid] = d;
        sInv[tid] = 1.f / fmaxf(bf2f(P.deg[d]), 1.f);
        const u16* ps = posit + ((size_t)bb * NN + s) * 3;
        const u16* pd = posit + ((size_t)bb * NN + d) * 3;
        float dx = bf2f(ps[0]) - bf2f(pd[0]);
        float dy = bf2f(ps[1]) - bf2f(pd[1]);
        float dz = bf2f(ps[2]) - bf2f(pd[2]);
        sRel[tid][0] = dx; sRel[tid][1] = dy; sRel[tid][2] = dz;
        sDist[tid] = sqrtf(dx * dx + dy * dy + dz * dz);
    }

    // gather h_src -> sX, h_dst -> sY (4 threads/row, 64B each)
    {
        const int r = tid >> 2, part = tid & 3;
        int slot = s0 + r; if (slot >= EE) slot = EE - 1;
        int e = P.es[slot];
        int s = P.eidx[e];
        int d = P.eidx[EE + e];
        const uint4* fs = (const uint4*)(feat + ((size_t)bb * NN + s) * HH);
        const uint4* fd = (const uint4*)(feat + ((size_t)bb * NN + d) * HH);
        uint4* as = (uint4*)&sX[r][part * 32];
        uint4* ad = (uint4*)&sY[r][part * 32];
#pragma unroll
        for (int i = 0; i < 4; ++i) { as[i] = fs[part * 4 + i]; ad[i] = fd[part * 4 + i]; }
    }
    __syncthreads();   // B1

    const int nt = wv;
    const int mrow = lane & 15;
    const int kq = (lane >> 4) * 8;
    const int crow = (lane >> 4) * 4;
    const int ccol = lane & 15;
    const int col = nt * 16 + ccol;

    f32x4 acc[8];
#pragma unroll
    for (int mt = 0; mt < 8; ++mt) acc[mt] = (f32x4){0.f, 0.f, 0.f, 0.f};

    // ----- msg layer 1 : [h_src | h_dst] @ W1[0:256]  (K=256) -----
#pragma unroll
    for (int kt = 0; kt < 8; ++kt) {
        const u16* Xb = (kt < 4) ? &sX[0][0] : &sY[0][0];
        const int kk = (kt & 3) * 32 + kq;
        bf16x8 bw = *(const bf16x8*)(P.fW1 + (size_t)(((kt * 8 + nt) * 64 + lane) * 8));
#pragma unroll
        for (int mt = 0; mt < 8; ++mt) {
            bf16x8 a = *(const bf16x8*)(Xb + (mt * 16 + mrow) * 136 + kk);
            acc[mt] = MFMA(a, bw, acc[mt]);
        }
    }
    __syncthreads();   // B2: all L1 reads of sX/sY done

    // epilogue: + dist*W1[256] + b1, silu -> sX
    {
        const float wl = bf2f(P.w1last[col]);
        const float bb2 = bf2f(P.bias1[col]);
#pragma unroll
        for (int mt = 0; mt < 8; ++mt) {
#pragma unroll
            for (int r = 0; r < 4; ++r) {
                const int row = mt * 16 + crow + r;
                float z = fmaf(sDist[row], wl, acc[mt][r]) + bb2;
                sX[row][col] = f2bf(silu_f(z));
            }
        }
    }
    __syncthreads();   // B3

    // ----- msg layer 2 : sX @ W2 + b2 = messages -> sY (K=128) -----
#pragma unroll
    for (int mt = 0; mt < 8; ++mt) acc[mt] = (f32x4){0.f, 0.f, 0.f, 0.f};
#pragma unroll
    for (int kt = 0; kt < 4; ++kt) {
        const int kk = kt * 32 + kq;
        bf16x8 bw = *(const bf16x8*)(P.fW2 + (size_t)(((kt * 8 + nt) * 64 + lane) * 8));
#pragma unroll
        for (int mt = 0; mt < 8; ++mt) {
            bf16x8 a = *(const bf16x8*)(&sX[0][0] + (mt * 16 + mrow) * 136 + kk);
            acc[mt] = MFMA(a, bw, acc[mt]);
        }
    }
    {
        const float bb2 = bf2f(P.bias2[col]);
#pragma unroll
        for (int mt = 0; mt < 8; ++mt) {
#pragma unroll
            for (int r = 0; r < 4; ++r) {
                const int row = mt * 16 + crow + r;
                sY[row][col] = f2bf(acc[mt][r] + bb2);
            }
        }
    }
    __syncthreads();   // B4: messages visible; all reads of sX done

    // ----- pos layer 1 : silu(messages @ P1 + bp1) -> sX (K=128) -----
#pragma unroll
    for (int mt = 0; mt < 8; ++mt) acc[mt] = (f32x4){0.f, 0.f, 0.f, 0.f};
#pragma unroll
    for (int kt = 0; kt < 4; ++kt) {
        const int kk = kt * 32 + kq;
        bf16x8 bw = *(const bf16x8*)(P.fP1 + (size_t)(((kt * 8 + nt) * 64 + lane) * 8));
#pragma unroll
        for (int mt = 0; mt < 8; ++mt) {
            bf16x8 a = *(const bf16x8*)(&sY[0][0] + (mt * 16 + mrow) * 136 + kk);
            acc[mt] = MFMA(a, bw, acc[mt]);
        }
    }

    // segment-reduced scatter of messages (rows sorted by dst):
    // 512 threads = 128 cols x 4 row-spans of 32, pre-scaled by 1/clip(deg);
    // replicated tail rows (slot >= EE) contribute 0
    {
        const int scol = tid & 127;
        const int r0 = (tid >> 7) * 32;
        float accv = 0.f;
        int dprev = sDst[r0];
        float invprev = sInv[r0];
#pragma unroll 1
        for (int r = r0; r < r0 + 32; ++r) {
            int dcur = sDst[r];
            if (dcur != dprev) {
                unsafeAtomicAdd(&msg_acc[(size_t)dprev * HH + scol], accv * invprev);
                accv = 0.f; dprev = dcur; invprev = sInv[r];
            }
            float x = bf2f(sY[r][scol]);
            accv += (s0 + r < EE) ? x : 0.f;
        }
        unsafeAtomicAdd(&msg_acc[(size_t)dprev * HH + scol], accv * invprev);
    }

    // pos1 epilogue -> sX
    {
        const float bb2 = bf2f(P.biasp1[col]);
#pragma unroll
        for (int mt = 0; mt < 8; ++mt) {
#pragma unroll
            for (int r = 0; r < 4; ++r) {
                const int row = mt * 16 + crow + r;
                sX[row][col] = f2bf(silu_f(acc[mt][r] + bb2));
            }
        }
    }
    __syncthreads();   // B5

    // ----- pos layer 2 : tanh(hidden @ p2 + bp2) ; scatter wgt*rel_pos -----
    {
        const int r = tid >> 2, q = tid & 3;   // 4 threads/row, 32 cols each
        const unsigned* t32 = (const unsigned*)&sX[r][q * 32];
        const unsigned* w32 = (const unsigned*)(P.wp2 + q * 32);
        float p = 0.f;
#pragma unroll
        for (int k = 0; k < 16; ++k) {
            unsigned a = t32[k], b = w32[k];
            union { unsigned i; float f; } al, ah, bl, bh;
            al.i = a << 16; ah.i = a & 0xffff0000u;
            bl.i = b << 16; bh.i = b & 0xffff0000u;
            p = fmaf(al.f, bl.f, p);
            p = fmaf(ah.f, bh.f, p);
        }
        p += __shfl_xor(p, 1);
        p += __shfl_xor(p, 2);
        if (q == 0 && s0 + r < EE) {
            float wgt = tanhf(p + bf2f(P.biasp2[0]));
            const size_t pb = (size_t)sDst[r] * 3;
            unsafeAtomicAdd(&pos_acc[pb + 0], wgt * sRel[r][0]);
            unsafeAtomicAdd(&pos_acc[pb + 1], wgt * sRel[r][1]);
            unsafeAtomicAdd(&pos_acc[pb + 2], wgt * sRel[r][2]);
        }
    }
}

// ---------------- update + fused pos output ----------------
__global__ __launch_bounds__(256) void update_kernel(
    const void* __restrict__ rawfeat, const void* __restrict__ rawpos,
    const u16* __restrict__ fU1, const u16* __restrict__ bu1,
    const u16* __restrict__ fU2, const u16* __restrict__ bu2,
    void* __restrict__ outp, const float* __restrict__ magg, const float* __restrict__ pacc,
    const int* __restrict__ flag)
{
    const int tid = threadIdx.x;
    const int lane = tid & 63;
    const int wv = tid >> 6;
    const int row0 = blockIdx.x * 64;
    const int isf = *flag;

    __shared__ u16 sA[64][136];   // features (bf16)
    __shared__ u16 sB[64][136];   // msg_acc -> hidden (reused)

    if (isf) {
        const float* fp = (const float*)rawfeat + (size_t)row0 * HH;
        for (int i = tid; i < 1024; i += 256) {
            int r = i >> 4, c = (i & 15) * 8;
            float4 v0 = *(const float4*)(fp + (size_t)r * HH + c);
            float4 v1 = *(const float4*)(fp + (size_t)r * HH + c + 4);
            uint4 o;
            o.x = (unsigned)f2bf(v0.x) | ((unsigned)f2bf(v0.y) << 16);
            o.y = (unsigned)f2bf(v0.z) | ((unsigned)f2bf(v0.w) << 16);
            o.z = (unsigned)f2bf(v1.x) | ((unsigned)f2bf(v1.y) << 16);
            o.w = (unsigned)f2bf(v1.z) | ((unsigned)f2bf(v1.w) << 16);
            *(uint4*)&sA[r][c] = o;
        }
    } else {
        const uint4* fp = (const uint4*)((const u16*)rawfeat + (size_t)row0 * HH);
        for (int i = tid; i < 1024; i += 256) {
            int r = i >> 4, c = i & 15;
            *(uint4*)&sA[r][c * 8] = fp[i];
        }
    }
    {
        const float4* am = (const float4*)(magg) + (size_t)row0 * 32;
        for (int i = tid; i < 2048; i += 256) {
            int r = i >> 5;
            float4 v = am[i];
            int c = (i & 31) * 4;
            sB[r][c + 0] = f2bf(v.x);
            sB[r][c + 1] = f2bf(v.y);
            sB[r][c + 2] = f2bf(v.z);
            sB[r][c + 3] = f2bf(v.w);
        }
    }
    __syncthreads();

    const int nt0 = wv * 2;
    const int mrow = lane & 15;
    const int kq = (lane >> 4) * 8;
    const int crow = (lane >> 4) * 4;
    const int ccol = lane & 15;

    f32x4 acc[4][2];
#pragma unroll
    for (int mt = 0; mt < 4; ++mt) {
        acc[mt][0] = (f32x4){0.f, 0.f, 0.f, 0.f};
        acc[mt][1] = (f32x4){0.f, 0.f, 0.f, 0.f};
    }
#pragma unroll
    for (int kt = 0; kt < 8; ++kt) {
        const u16* Xb = (kt < 4) ? &sA[0][0] : &sB[0][0];
        const int kk = (kt & 3) * 32 + kq;
        bf16x8 bw0 = *(const bf16x8*)(fU1 + (size_t)(((kt * 8 + nt0) * 64 + lane) * 8));
        bf16x8 bw1 = *(const bf16x8*)(fU1 + (size_t)(((kt * 8 + nt0 + 1) * 64 + lane) * 8));
#pragma unroll
        for (int mt = 0; mt < 4; ++mt) {
            bf16x8 a = *(const bf16x8*)(Xb + (mt * 16 + mrow) * 136 + kk);
            acc[mt][0] = MFMA(a, bw0, acc[mt][0]);
            acc[mt][1] = MFMA(a, bw1, acc[mt][1]);
        }
    }
    __syncthreads();

#pragma unroll
    for (int mt = 0; mt < 4; ++mt) {
#pragma unroll
        for (int n2 = 0; n2 < 2; ++n2) {
            const int col = (nt0 + n2) * 16 + ccol;
            const float bb = bf2f(bu1[col]);
#pragma unroll
            for (int r = 0; r < 4; ++r) {
                const int row = mt * 16 + crow + r;
                sB[row][col] = f2bf(silu_f(acc[mt][n2][r] + bb));
            }
        }
    }
    __syncthreads();

#pragma unroll
    for (int mt = 0; mt < 4; ++mt) {
        acc[mt][0] = (f32x4){0.f, 0.f, 0.f, 0.f};
        acc[mt][1] = (f32x4){0.f, 0.f, 0.f, 0.f};
    }
#pragma unroll
    for (int kt = 0; kt < 4; ++kt) {
        const int kk = kt * 32 + kq;
        bf16x8 bw0 = *(const bf16x8*)(fU2 + (size_t)(((kt * 8 + nt0) * 64 + lane) * 8));
        bf16x8 bw1 = *(const bf16x8*)(fU2 + (size_t)(((kt * 8 + nt0 + 1) * 64 + lane) * 8));
#pragma unroll
        for (int mt = 0; mt < 4; ++mt) {
            bf16x8 a = *(const bf16x8*)(&sB[0][0] + (mt * 16 + mrow) * 136 + kk);
            acc[mt][0] = MFMA(a, bw0, acc[mt][0]);
            acc[mt][1] = MFMA(a, bw1, acc[mt][1]);
        }
    }
#pragma unroll
    for (int mt = 0; mt < 4; ++mt) {
#pragma unroll
        for (int n2 = 0; n2 < 2; ++n2) {
            const int col = (nt0 + n2) * 16 + ccol;
            const float bb = bf2f(bu2[col]);
#pragma unroll
            for (int r = 0; r < 4; ++r) {
                const int row = mt * 16 + crow + r;
                const size_t idx = (size_t)(row0 + row) * HH + col;
                if (isf) {
                    float base = ((const float*)rawfeat)[idx];
                    ((float*)outp)[idx] = acc[mt][n2][r] + bb + base;
                } else {
                    float base = bf2f(sA[row][col]);
                    ((u16*)outp)[idx] = f2bf(acc[mt][n2][r] + bb + base);
                }
            }
        }
    }

    // fused positions output: 3 elems per node row (192 per block)
    if (tid < 192) {
        int i = row0 * 3 + tid;
        float x = pacc[i];
        if (isf) {
            float base = ((const float*)rawpos)[i];
            ((float*)outp)[5120000 + i] = base + 0.5f * x;
        } else {
            float base = bf2f(((const u16*)rawpos)[i]);
            ((u16*)outp)[5120000 + i] = f2bf(base + 0.5f * x);
        }
    }
}

extern "C" void kernel_launch(void* const* d_in, const int* in_sizes, int n_in,
                              void* d_out, int out_size, void* d_ws, size_t ws_size,
                              hipStream_t stream)
{
    // ws layout (bytes): identical to round 9/10
    float* ws_msg  = (float*)d_ws;
    float* ws_pos  = (float*)((char*)d_ws + 20480000);
    int*   cnt_up  = (int*)((char*)d_ws + 20960000);
    int*   cnt_dn  = (int*)((char*)d_ws + 21040000);
    int*   cur_up  = (int*)((char*)d_ws + 21120000);
    int*   cur_dn  = (int*)((char*)d_ws + 21200000);
    int*   bsum_up = (int*)((char*)d_ws + 21280000);
    int*   bsum_dn = (int*)((char*)d_ws + 21280400);
    int*   es_up   = (int*)((char*)d_ws + 21280800);
    int*   es_dn   = (int*)((char*)d_ws + 22080800);
    u16*   fbase   = (u16*)((char*)d_ws + 22880800);
    u16*   canon   = (u16*)((char*)d_ws + 23241248);
    int*   flag    = (int*)((char*)d_ws + 33804328);
    if (ws_size < 33804332ULL) return;

    u16* f_m1u = fbase;              // 32768 (K=256)
    u16* f_m2u = fbase + 32768;
    u16* f_p1u = fbase + 49152;
    u16* f_m1d = fbase + 65536;
    u16* f_m2d = fbase + 98304;
    u16* f_p1d = fbase + 114688;
    u16* f_u1  = fbase + 131072;
    u16* f_u2  = fbase + 163840;

    u16* cfeat  = canon;
    u16* cpos   = canon + 5120000;
    u16* cdgu   = canon + 5240000;
    u16* cdgd   = canon + 5260000;
    u16* cw1lu  = canon + 5280000;
    u16* cb1u   = canon + 5280128;
    u16* cb2u   = canon + 5280256;
    u16* cbp1u  = canon + 5280384;
    u16* cwp2u  = canon + 5280512;
    u16* cbp2u  = canon + 5280640;
    u16* cw1ld  = canon + 5280642;
    u16* cb1d   = canon + 5280770;
    u16* cb2d   = canon + 5280898;
    u16* cbp1d  = canon + 5281026;
    u16* cwp2d  = canon + 5281154;
    u16* cbp2d  = canon + 5281282;
    u16* cbu1   = canon + 5281284;
    u16* cbu2   = canon + 5281412;

    const int* ei_up = (const int*)d_in[2];
    const int* ei_dn = (const int*)d_in[3];

    // launch 1: detect dtype + zero CSR counters
    detect_zero_kernel<<<157, 256, 0, stream>>>((const u16*)d_in[0], flag, cnt_up);

    // launch 2: fused setup (ws zero | canon | frags | edge counts)
    P18 cp;
    cp.p[0] = d_in[0];  cp.p[1] = d_in[1];  cp.p[2] = d_in[4];  cp.p[3] = d_in[5];
    cp.p[4] = d_in[6];  cp.p[5] = d_in[7];  cp.p[6] = d_in[9];  cp.p[7] = d_in[11];
    cp.p[8] = d_in[12]; cp.p[9] = d_in[13];
    cp.p[10] = d_in[14]; cp.p[11] = d_in[15]; cp.p[12] = d_in[17]; cp.p[13] = d_in[19];
    cp.p[14] = d_in[20]; cp.p[15] = d_in[21];
    cp.p[16] = d_in[23]; cp.p[17] = d_in[25];
    P8 wsf;
    wsf.w[0] = d_in[6];  wsf.w[1] = d_in[8];  wsf.w[2] = d_in[10]; wsf.w[3] = d_in[14];
    wsf.w[4] = d_in[16]; wsf.w[5] = d_in[18]; wsf.w[6] = d_in[22]; wsf.w[7] = d_in[24];
    setup_kernel<<<(R3 + 255) / 256, 256, 0, stream>>>(cp, wsf, ei_up, ei_dn,
                                                       ws_msg, canon, fbase,
                                                       cnt_up, cnt_dn, flag);

    // launches 3-5: CSR scan + scatter
    SP sp;
    sp.cnt[0] = cnt_up; sp.cnt[1] = cnt_dn;
    sp.cur[0] = cur_up; sp.cur[1] = cur_dn;
    sp.bsum[0] = bsum_up; sp.bsum[1] = bsum_dn;
    scan1_kernel<<<2 * NBLK, 256, 0, stream>>>(sp);
    scan2_kernel<<<1, 256, 0, stream>>>(bsum_up, bsum_dn);
    scatter2_kernel<<<(2 * EE + 255) / 256, 256, 0, stream>>>(ei_up, ei_dn, cur_up, bsum_up,
                                                              cur_dn, bsum_dn, es_up, es_dn);

    // launch 6: edge kernel (128 rows/block)
    EP up, dn;
    up.eidx = ei_up; up.es = es_up; up.deg = cdgu;
    up.fW1 = f_m1u; up.fW2 = f_m2u; up.fP1 = f_p1u;
    up.w1last = cw1lu; up.bias1 = cb1u; up.bias2 = cb2u;
    up.biasp1 = cbp1u; up.wp2 = cwp2u; up.biasp2 = cbp2u;
    dn.eidx = ei_dn; dn.es = es_dn; dn.deg = cdgd;
    dn.fW1 = f_m1d; dn.fW2 = f_m2d; dn.fP1 = f_p1d;
    dn.w1last = cw1ld; dn.bias1 = cb1d; dn.bias2 = cb2d;
    dn.biasp1 = cbp1d; dn.wp2 = cwp2d; dn.biasp2 = cbp2d;
    edge_kernel<<<2 * BB * NEB, 512, 0, stream>>>(cfeat, cpos, up, dn, ws_msg, ws_pos);

    // launch 7: update + positions out
    update_kernel<<<625, 256, 0, stream>>>(d_in[0], d_in[1], f_u1, cbu1, f_u2, cbu2,
                                           d_out, ws_msg, ws_pos, flag);
}